// Round 12
// baseline (145.588 us; speedup 1.0000x reference)
//
#include <hip/hip_runtime.h>

// ---------------------------------------------------------------------------
// r[b,v] = sum_c (feats[b,c,v] - m[c,v]) / s[c,v] * weights[v,c] + bias[v]
// feats per scale k: GEMM  fmap_k (B*Ck x K=n^2)  @  prf_k^T (K x V)
// Fused epilogue: feats tile * w'[c,v]=weights[v,c]/s[c,v], c-reduced,
// atomicAdd into out (pre-initialized with off[v] = bias - sum m*w').
//
// R11 = R8 (best, 110us) + two deltas:
//  * B fragments direct-to-register from frag-ordered bf16 ws tiles
//    (no lds_b): LDS 48->32KB -> 4 blocks/CU; LDS traffic 144->96KB/step.
//    B loads issued between the two barriers; sync2's vmcnt(0) drains them
//    for free.
//  * Epilogue reads w' from a TRANSPOSED table wpt[v][c] -> one f32x4 per
//    (i,j) instead of 4 scalar stride-2KB gathers.
// Hot loop otherwise identical to R8: raw-fp32-A global_load_lds into a
// 32KB swizzled LDS tile, 2 __syncthreads per step, fp32 frag-read + cvt.
// ---------------------------------------------------------------------------

typedef float f32x4 __attribute__((ext_vector_type(4)));
typedef f32x4 __attribute__((aligned(4))) f32x4u;
typedef __bf16 bf16x4 __attribute__((ext_vector_type(4)));
typedef __bf16 bf16x8 __attribute__((ext_vector_type(8)));

#define TILE_E 8192              // elems per [128x64] tile
#define V_DIM 512
#define C_TOT 960
#define B_DIM 128

#define NBT 268                  // B tiles: 4 col-groups x (49+13+4+1)
#define NRA 896                  // ragged-A images: 128(s1)+256(s2)+512(s3)
#define PREP_WP 1920
#define PREP_OFF 512
#define PREP_BLKS (NBT + NRA + PREP_WP + PREP_OFF)

#define GEMM_BLKS 6144           // 1024(s0)+512(s1)+1024(s2)+3584(tail) = 8*768

// workspace layout (bytes): [wpt][bt][ra]
#define WP_BYTES 1966080L                   // 960*512*4 (v-major)
#define BT_BYTES ((long)NBT * TILE_E * 2)   // 4,390,912
#define RA_BYTES ((long)NRA * TILE_E * 2)   // 14,680,064
#define WS_NEED  (WP_BYTES + BT_BYTES + RA_BYTES)

static __device__ __forceinline__ bf16x8 cvt8(f32x4 lo, f32x4 hi) {
  return bf16x8{(__bf16)lo[0], (__bf16)lo[1], (__bf16)lo[2], (__bf16)lo[3],
                (__bf16)hi[0], (__bf16)hi[1], (__bf16)hi[2], (__bf16)hi[3]};
}

// T2 XOR-swizzle, 16B granularity, inside a [128][64]-elem bf16 tile
static __device__ __forceinline__ int swz_idx(int row, int k) {
  return row * 64 + (((k >> 3) ^ (row & 7)) << 3) + (k & 7);
}

// ---------------------------------------------------------------------------
// Fused GEMM, single launch (requires ws). Decode after XCD interleave:
//   w in [0,1024): s0 full steps (fp32-A), split-K x4
//   w in [1024,1536): s1 full steps 0..11
//   w in [1536,2560): s2 full steps 0..2
//   w in [2560,6144): tail (1 bf16-image step): s1@12, s2@3, s3@0
// ---------------------------------------------------------------------------
__global__ __launch_bounds__(256, 4)
void gemm_all(const float* __restrict__ f0, const float* __restrict__ f1,
              const float* __restrict__ f2,
              const __bf16* __restrict__ bt,   // frag-ordered B tiles
              const __bf16* __restrict__ ra,   // ragged-A swz bf16 images
              const float* __restrict__ wpt,   // [V, C_TOT] transposed w'
              float* __restrict__ out)         // [B, V]
{
  __shared__ float lds_af[TILE_E];   // 32 KB fp32 A (tail reuses as bf16)

  const int tid  = threadIdx.x;
  const int lane = tid & 63;
  const int wid  = tid >> 6;
  const int wm   = wid >> 1;
  const int wn   = wid & 1;

  // XCD-interleaved, x-quad-preserving decode: 4 N-siblings of one A-panel
  // co-locate on an XCD; LPT order (long blocks first).
  const int bid   = blockIdx.x;
  const int sslot = bid >> 3;
  const int xcd   = bid & 7;
  const int w     = (((sslot >> 2) << 3) + xcd) * 4 + (sslot & 3);

  f32x4 acc[4][4];
#pragma unroll
  for (int i = 0; i < 4; ++i)
#pragma unroll
    for (int j = 0; j < 4; ++j)
      acc[i][j] = f32x4{0.f, 0.f, 0.f, 0.f};

  int Ck, Coff, bn_g, bn;
  long bm;

  // B fragment loads: frag-ordered tile -> 8 coalesced dwordx4 per wave
  auto load_b = [&](const __bf16* tbp, bf16x8* br) {
#pragma unroll
    for (int j = 0; j < 4; ++j)
#pragma unroll
      for (int kc = 0; kc < 2; ++kc)
        br[j * 2 + kc] = *(const bf16x8*)(
            tbp + ((((wn * 4 + j) * 2 + kc) << 6) + lane) * 8);
  };

  if (w < 2560) {
    // ======================= MAIN: fp32-A full steps =======================
    const float* fmap; int K, nst, bbase, y, s0k, sendk;
    if (w < 1024) {
      fmap = f0; K = 3136; nst = 49; bbase = 0; Ck = 64; Coff = 0;
      bn_g = w & 3; y = (w >> 2) & 63;
      const int z = w >> 8; s0k = z * 12; sendk = (z == 3) ? 49 : s0k + 12;
    } else if (w < 1536) {
      const int l = w - 1024;
      fmap = f1; K = 784; nst = 13; bbase = 196; Ck = 128; Coff = 64;
      bn_g = l & 3; y = l >> 2; s0k = 0; sendk = 12;
    } else {
      const int l = w - 1536;
      fmap = f2; K = 196; nst = 4; bbase = 248; Ck = 256; Coff = 192;
      bn_g = l & 3; y = l >> 2; s0k = 0; sendk = 3;
    }
    bm = (long)y * 128; bn = bn_g * 128;

    for (int ks = s0k; ks < sendk; ++ks) {
      __syncthreads();   // previous step's LDS readers done

      // stage A: raw fp32, inverse-swizzled per-lane source, linear dest
      const float* ab = fmap + bm * (long)K + (long)ks * 64;
#pragma unroll
      for (int i = 0; i < 8; ++i) {
        const int seg = wid * 8 + i;
        const int cc  = seg * 64 + lane;       // dest 16B-chunk 0..2047
        const int row = cc >> 4;
        const int q4  = (cc & 15) ^ (row & 7); // source 4-float chunk
        __builtin_amdgcn_global_load_lds(
            (const __attribute__((address_space(1))) void*)(ab + (long)row * K + q4 * 4),
            (__attribute__((address_space(3))) void*)(&lds_af[seg * 256]),
            16, 0, 0);
      }
      // B fragments -> regs (drained together with the stage at sync2)
      bf16x8 breg[8];
      load_b(bt + (long)(bbase + bn_g * nst + ks) * TILE_E, breg);

      __syncthreads();   // drains gl_lds + breg (vmcnt 0) -> no wait at MFMA

      // fragments: A = 2x ds_read_b128 fp32 + cast; B already in regs
#pragma unroll
      for (int kc = 0; kc < 2; ++kc) {
        const int q4a = kc * 8 + ((lane >> 4) << 1);
        bf16x8 af[4];
#pragma unroll
        for (int i = 0; i < 4; ++i) {
          const int r = wm * 64 + i * 16 + (lane & 15);
          const f32x4 fa = *(const f32x4*)&lds_af[r * 64 + ((q4a ^ (r & 7)) << 2)];
          const f32x4 fb = *(const f32x4*)&lds_af[r * 64 + (((q4a + 1) ^ (r & 7)) << 2)];
          af[i] = cvt8(fa, fb);
        }
#pragma unroll
        for (int i = 0; i < 4; ++i)
#pragma unroll
          for (int j = 0; j < 4; ++j)
            acc[i][j] = __builtin_amdgcn_mfma_f32_16x16x32_bf16(
                af[i], breg[j * 2 + kc], acc[i][j], 0, 0, 0);
      }
    }
  } else {
    // ================== TAIL: one bf16-image step per block =================
    const int l = w - 2560;
    int y, btile;
    long raidx;
    if (l < 512) {
      y = l >> 2; bn_g = l & 3; raidx = y;          Ck = 128; Coff = 64;
      btile = 196 + bn_g * 13 + 12;
    } else if (l < 1536) {
      const int m = l - 512;
      y = m >> 2; bn_g = m & 3; raidx = 128 + y;    Ck = 256; Coff = 192;
      btile = 248 + bn_g * 4 + 3;
    } else {
      const int m = l - 1536;
      y = m >> 2; bn_g = m & 3; raidx = 384 + y;    Ck = 512; Coff = 448;
      btile = 264 + bn_g;
    }
    bm = (long)y * 128; bn = bn_g * 128;

    __bf16* lds_ab = (__bf16*)lds_af;
    const __bf16* asrc = ra + raidx * TILE_E;
#pragma unroll
    for (int i = 0; i < 4; ++i) {
      const int seg = wid * 4 + i;
      __builtin_amdgcn_global_load_lds(
          (const __attribute__((address_space(1))) void*)(asrc + seg * 512 + lane * 8),
          (__attribute__((address_space(3))) void*)(&lds_ab[seg * 512]),
          16, 0, 0);
    }
    bf16x8 breg[8];
    load_b(bt + (long)btile * TILE_E, breg);
    __syncthreads();

#pragma unroll
    for (int kc = 0; kc < 2; ++kc) {
      const int cx = kc * 4 + (lane >> 4);
      bf16x8 af[4];
#pragma unroll
      for (int i = 0; i < 4; ++i) {
        const int r = wm * 64 + i * 16 + (lane & 15);
        af[i] = *(const bf16x8*)&lds_ab[r * 64 + ((cx ^ (r & 7)) << 3)];
      }
#pragma unroll
      for (int i = 0; i < 4; ++i)
#pragma unroll
        for (int j = 0; j < 4; ++j)
          acc[i][j] = __builtin_amdgcn_mfma_f32_16x16x32_bf16(
              af[i], breg[j * 2 + kc], acc[i][j], 0, 0, 0);
    }
  }

  // ---- epilogue: per-wave 64x64 feats sub-tile, c-reduce, atomicAdd.
  // C/D layout: frag row = (lane>>4)*4 + reg, frag col = lane&15   [m89]
  const long mbase = bm + wm * 64;
  const int  bidx  = (int)(mbase / Ck);
  const int  cbase = (int)(mbase % Ck) + Coff;
  const int  lrow  = ((lane >> 4) << 2);
  const int  lcol  = lane & 15;

#pragma unroll
  for (int j = 0; j < 4; ++j) {
    const int v = bn + wn * 64 + j * 16 + lcol;
    float s = 0.f;
#pragma unroll
    for (int i = 0; i < 4; ++i) {
      const int cg = cbase + i * 16 + lrow;
      const f32x4 w4 = *(const f32x4*)&wpt[(long)v * C_TOT + cg];
      s += acc[i][j][0] * w4[0] + acc[i][j][1] * w4[1]
         + acc[i][j][2] * w4[2] + acc[i][j][3] * w4[3];
    }
    s += __shfl_xor(s, 16);
    s += __shfl_xor(s, 32);
    if (lane < 16)
      atomicAdd(&out[(long)bidx * V_DIM + v], s);
  }
}

// ---------------------------------------------------------------------------
// Ragged-A image convert: img[swz_idx(row,k)] = src[rbase+row, ks*64+k],
// zero-padded past K.
// ---------------------------------------------------------------------------
static __device__ __forceinline__ void conv_tile(const float* __restrict__ src,
                                                 int K, long rbase, int ks,
                                                 __bf16* __restrict__ dst, int tid)
{
#pragma unroll
  for (int it = 0; it < 4; ++it) {
    const int u   = tid + it * 256;
    const int row = u >> 3;
    const int q8  = u & 7;
    const int k   = ((q8 ^ (row & 7)) << 3);
    const long gk = (long)ks * 64 + k;
    const float* sp = src + (rbase + row) * (long)K + gk;
    bf16x8 h;
    if (gk + 8 <= K) {
      h = cvt8(*(const f32x4u*)sp, *(const f32x4u*)(sp + 4));
    } else {
#pragma unroll
      for (int e = 0; e < 8; ++e)
        h[e] = (__bf16)((gk + e < K) ? sp[e] : 0.f);
    }
    *(bf16x8*)&dst[(long)row * 64 + q8 * 8] = h;
  }
}

// ---------------------------------------------------------------------------
// One prep launch: [0,268) B frag-ordered tiles; [268,1164) ragged-A images;
// then wpt (v-major w'); then out init with the constant term.
// B tile layout: dst[((fj*2+kc)*64 + l)*8 + e] =
//   B[g*128 + fj*16 + (l&15), ks*64 + kc*32 + ((l>>4)<<3) + e]  (0-padded)
// ---------------------------------------------------------------------------
__global__ void prep_all(const float* __restrict__ f1, const float* __restrict__ f2,
                         const float* __restrict__ f3,
                         const float* __restrict__ p0, const float* __restrict__ p1,
                         const float* __restrict__ p2, const float* __restrict__ p3,
                         const float* __restrict__ weights,
                         const float* __restrict__ bias,
                         const float* __restrict__ fm,
                         const float* __restrict__ fs,
                         float* __restrict__ wpt,     // may be null
                         __bf16* __restrict__ bt,     // may be null
                         __bf16* __restrict__ ra,     // may be null
                         float* __restrict__ out)
{
  __shared__ float red[4];
  const int blk = blockIdx.x;
  const int tid = threadIdx.x;

  if (blk < NBT) {
    if (!bt) return;
    int t = blk; const float* src; int K, g, ks;
    if (t < 196)      { src = p0; K = 3136; g = t / 49; ks = t % 49; }
    else if (t < 248) { t -= 196; src = p1; K = 784; g = t / 13; ks = t % 13; }
    else if (t < 264) { t -= 248; src = p2; K = 196; g = t / 4;  ks = t % 4; }
    else              { t -= 264; src = p3; K = 49;  g = t;      ks = 0; }
    __bf16* dst = bt + (long)blk * TILE_E;
#pragma unroll
    for (int it = 0; it < 4; ++it) {
      const int c2 = tid + it * 256;
      const int fj = c2 >> 7;
      const int kc = (c2 >> 6) & 1;
      const int l  = c2 & 63;
      const int row  = g * 128 + fj * 16 + (l & 15);
      const int kcol = ks * 64 + kc * 32 + ((l >> 4) << 3);
      const float* sp = src + (long)row * K + kcol;
      bf16x8 h;
      if (kcol + 8 <= K) {
        h = cvt8(*(const f32x4u*)sp, *(const f32x4u*)(sp + 4));
      } else {
#pragma unroll
        for (int e = 0; e < 8; ++e)
          h[e] = (__bf16)((kcol + e < K) ? sp[e] : 0.f);
      }
      *(bf16x8*)&dst[(long)c2 * 8] = h;
    }
  } else if (blk < NBT + NRA) {
    if (!ra) return;
    const int t = blk - NBT; const float* src; int K, ks; long rbase;
    if (t < 128)      { src = f1; K = 784; ks = 12; rbase = (long)t * 128; }
    else if (t < 384) { src = f2; K = 196; ks = 3;  rbase = (long)(t - 128) * 128; }
    else              { src = f3; K = 49;  ks = 0;  rbase = (long)(t - 384) * 128; }
    conv_tile(src, K, rbase, ks, ra + (long)t * TILE_E, tid);
  } else if (blk < NBT + NRA + PREP_WP) {
    if (!wpt) return;
    const int idx = (blk - NBT - NRA) * 256 + tid;   // exactly 960*512
    const int v = idx / C_TOT;
    const int c = idx - v * C_TOT;
    wpt[idx] = weights[idx] / fs[(long)c * V_DIM + v];   // wpt layout == weights
  } else {
    const int v = blk - (NBT + NRA + PREP_WP);       // 0..511
    float s = 0.f;
    for (int c = tid; c < C_TOT; c += 256) {
      const long i = (long)c * V_DIM + v;
      s += fm[i] * weights[(long)v * C_TOT + c] / fs[i];
    }
#pragma unroll
    for (int o = 32; o; o >>= 1) s += __shfl_down(s, o);
    if ((tid & 63) == 0) red[tid >> 6] = s;
    __syncthreads();
    if (tid < B_DIM) {
      const float off = bias[v] - (red[0] + red[1] + red[2] + red[3]);
      out[(long)tid * V_DIM + v] = off;
    }
  }
}

// ---------------------------------------------------------------------------
// Fallback GEMM (ws too small): inline fp32 staging of both operands.
// ---------------------------------------------------------------------------
__global__ __launch_bounds__(256, 3)
void gemm_fb(const float* __restrict__ fmap, const float* __restrict__ prf,
             const float* __restrict__ weights, const float* __restrict__ fs,
             float* __restrict__ out,
             int Ck, int K, int Coff, int nsteps, int kchunks)
{
  __shared__ __bf16 lds_a[TILE_E];
  __shared__ __bf16 lds_b[TILE_E];
  const int tid = threadIdx.x, lane = tid & 63, wid = tid >> 6;
  const int wm = wid >> 1, wn = wid & 1;
  const long bm = (long)blockIdx.y * 128;
  const int bn = blockIdx.x * 128;
  const int z = blockIdx.z, qb = nsteps / kchunks, rb = nsteps % kchunks;
  const int s0 = z * qb + (z < rb ? z : rb);
  const int send = s0 + qb + (z < rb ? 1 : 0);

  f32x4 acc[4][4];
#pragma unroll
  for (int i = 0; i < 4; ++i)
#pragma unroll
    for (int j = 0; j < 4; ++j) acc[i][j] = f32x4{0.f, 0.f, 0.f, 0.f};

  for (int ks = s0; ks < send; ++ks) {
    __syncthreads();
#pragma unroll
    for (int i = 0; i < 8; ++i) {
      const int c = tid + i * 256, row = c >> 4, k0 = (c & 15) << 2;
      const long gk = (long)ks * 64 + k0;
      const float* ap = fmap + (bm + row) * (long)K + gk;
      const float* bp = prf + (long)(bn + row) * K + gk;
      float a[4], b[4];
#pragma unroll
      for (int e = 0; e < 4; ++e) {
        a[e] = (gk + e < K) ? ap[e] : 0.f;
        b[e] = (gk + e < K) ? bp[e] : 0.f;
      }
      bf16x4 ha = {(__bf16)a[0], (__bf16)a[1], (__bf16)a[2], (__bf16)a[3]};
      bf16x4 hb = {(__bf16)b[0], (__bf16)b[1], (__bf16)b[2], (__bf16)b[3]};
      *(bf16x4*)&lds_a[swz_idx(row, k0)] = ha;
      *(bf16x4*)&lds_b[swz_idx(row, k0)] = hb;
    }
    __syncthreads();
#pragma unroll
    for (int kc = 0; kc < 2; ++kc) {
      const int cx = kc * 4 + (lane >> 4);
      bf16x8 af[4], bfr[4];
#pragma unroll
      for (int i = 0; i < 4; ++i) {
        const int r = wm * 64 + i * 16 + (lane & 15);
        af[i] = *(const bf16x8*)&lds_a[r * 64 + ((cx ^ (r & 7)) << 3)];
      }
#pragma unroll
      for (int j = 0; j < 4; ++j) {
        const int r = wn * 64 + j * 16 + (lane & 15);
        bfr[j] = *(const bf16x8*)&lds_b[r * 64 + ((cx ^ (r & 7)) << 3)];
      }
#pragma unroll
      for (int i = 0; i < 4; ++i)
#pragma unroll
        for (int j = 0; j < 4; ++j)
          acc[i][j] = __builtin_amdgcn_mfma_f32_16x16x32_bf16(af[i], bfr[j],
                                                              acc[i][j], 0, 0, 0);
    }
  }

  const long mbase = bm + wm * 64;
  const int bidx = (int)(mbase / Ck);
  const int cbase = (int)(mbase % Ck) + Coff;
  const int lrow = ((lane >> 4) << 2), lcol = lane & 15;
#pragma unroll
  for (int j = 0; j < 4; ++j) {
    const int v = bn + wn * 64 + j * 16 + lcol;
    float s = 0.f;
#pragma unroll
    for (int i = 0; i < 4; ++i) {
      const int cg = cbase + i * 16 + lrow;
#pragma unroll
      for (int r = 0; r < 4; ++r) {
        const float wf = weights[(long)v * C_TOT + cg + r]
                         / fs[(long)(cg + r) * V_DIM + v];
        s += acc[i][j][r] * wf;
      }
    }
    s += __shfl_xor(s, 16);
    s += __shfl_xor(s, 32);
    if (lane < 16) atomicAdd(&out[(long)bidx * V_DIM + v], s);
  }
}

extern "C" void kernel_launch(void* const* d_in, const int* in_sizes, int n_in,
                              void* d_out, int out_size, void* d_ws, size_t ws_size,
                              hipStream_t stream)
{
  const float* fmap0   = (const float*)d_in[0];
  const float* prf0    = (const float*)d_in[1];
  const float* fmap1   = (const float*)d_in[2];
  const float* prf1    = (const float*)d_in[3];
  const float* fmap2   = (const float*)d_in[4];
  const float* prf2    = (const float*)d_in[5];
  const float* fmap3   = (const float*)d_in[6];
  const float* prf3    = (const float*)d_in[7];
  const float* weights = (const float*)d_in[8];
  const float* bias    = (const float*)d_in[9];
  const float* fm      = (const float*)d_in[10];
  const float* fs      = (const float*)d_in[11];
  float* out = (float*)d_out;

  const bool has_ws = ws_size >= (size_t)WS_NEED;
  float*  wpt = has_ws ? (float*)d_ws : nullptr;
  __bf16* bt  = has_ws ? (__bf16*)((char*)d_ws + WP_BYTES) : nullptr;
  __bf16* ra  = has_ws ? (__bf16*)((char*)d_ws + WP_BYTES + BT_BYTES) : nullptr;

  // 1) prep: B frag tiles + ragged-A images + wpt + out init
  prep_all<<<dim3(PREP_BLKS), dim3(256), 0, stream>>>(
      fmap1, fmap2, fmap3, prf0, prf1, prf2, prf3,
      weights, bias, fm, fs, wpt, bt, ra, out);

  // 2) GEMM
  if (has_ws) {
    gemm_all<<<dim3(GEMM_BLKS), dim3(256), 0, stream>>>(
        fmap0, fmap1, fmap2, bt, ra, wpt, out);
  } else {
    struct Scale { const float* fmap; const float* prf; int Ck, K, Coff, nst, kch; };
    const Scale sc[4] = {
      {fmap0, prf0,  64, 3136,   0, 49, 4},
      {fmap1, prf1, 128,  784,  64, 13, 2},
      {fmap2, prf2, 256,  196, 192,  4, 1},
      {fmap3, prf3, 512,   49, 448,  1, 1},
    };
    for (int k = 0; k < 4; ++k) {
      dim3 grid(4, B_DIM * sc[k].Ck / 128, sc[k].kch);
      gemm_fb<<<grid, dim3(256), 0, stream>>>(
          sc[k].fmap, sc[k].prf, weights, fs, out,
          sc[k].Ck, sc[k].K, sc[k].Coff, sc[k].nst, sc[k].kch);
    }
  }
}

// Round 13
// 138.290 us; speedup vs baseline: 1.0528x; 1.0528x over previous
//
#include <hip/hip_runtime.h>

// ---------------------------------------------------------------------------
// r[b,v] = sum_c (feats[b,c,v] - m[c,v]) / s[c,v] * weights[v,c] + bias[v]
// feats per scale k: GEMM  fmap_k (B*Ck x K=n^2)  @  prf_k^T (K x V)
// Fused epilogue: feats tile * w'[c,v], c-reduced, atomicAdd into out
// (pre-initialized with off[v] = bias - sum m*w').
//
// R12 = R8 + T4 counted-vmcnt pipeline:
//  * A staged raw-fp32 via global_load_lds into DOUBLE 32KB swizzled buffers,
//    prefetched 1 step ahead; raw s_barrier + s_waitcnt vmcnt(16) keeps the
//    prefetch IN FLIGHT across the barrier (R8's __syncthreads = vmcnt(0)
//    drained it -> ~400cy exposed latency/step; R10 never fixed this).
//  * B fragments direct-to-register (frag-ordered bf16 ws tiles), issued
//    BEFORE the stage so the FIFO leaves the prefetch un-drained.
//  * __launch_bounds__(256,2): no spill (R11's (256,4) forced 64 VGPR ->
//    47MB scratch writes).
//  * Epilogue reads w' from transposed wpt[v][c] via f32x4.
// ---------------------------------------------------------------------------

typedef float f32x4 __attribute__((ext_vector_type(4)));
typedef f32x4 __attribute__((aligned(4))) f32x4u;
typedef __bf16 bf16x4 __attribute__((ext_vector_type(4)));
typedef __bf16 bf16x8 __attribute__((ext_vector_type(8)));

#define TILE_E 8192              // elems per [128x64] tile
#define V_DIM 512
#define C_TOT 960
#define B_DIM 128

#define NBT 268                  // B tiles: 4 col-groups x (49+13+4+1)
#define NRA 896                  // ragged-A images: 128(s1)+256(s2)+512(s3)
#define PREP_WP 1920
#define PREP_OFF 512
#define PREP_BLKS (NBT + NRA + PREP_WP + PREP_OFF)

#define GEMM_BLKS 6144           // 1024(s0)+512(s1)+1024(s2)+3584(tail) = 8*768

// workspace layout (bytes): [wpt][bt][ra]
#define WP_BYTES 1966080L                   // 960*512*4 (v-major)
#define BT_BYTES ((long)NBT * TILE_E * 2)   // 4,390,912
#define RA_BYTES ((long)NRA * TILE_E * 2)   // 14,680,064
#define WS_NEED  (WP_BYTES + BT_BYTES + RA_BYTES)

static __device__ __forceinline__ bf16x8 cvt8(f32x4 lo, f32x4 hi) {
  return bf16x8{(__bf16)lo[0], (__bf16)lo[1], (__bf16)lo[2], (__bf16)lo[3],
                (__bf16)hi[0], (__bf16)hi[1], (__bf16)hi[2], (__bf16)hi[3]};
}

// T2 XOR-swizzle, 16B granularity, inside a [128][64]-elem bf16 tile
static __device__ __forceinline__ int swz_idx(int row, int k) {
  return row * 64 + (((k >> 3) ^ (row & 7)) << 3) + (k & 7);
}

// ---------------------------------------------------------------------------
// Fused GEMM, single launch (requires ws). Decode after XCD interleave:
//   w in [0,1024): s0 full steps, split-K x4
//   w in [1024,1536): s1 full steps 0..11
//   w in [1536,2560): s2 full steps 0..2
//   w in [2560,6144): tail (1 bf16-image step): s1@12, s2@3, s3@0
// ---------------------------------------------------------------------------
__global__ __launch_bounds__(256, 2)
void gemm_all(const float* __restrict__ f0, const float* __restrict__ f1,
              const float* __restrict__ f2,
              const __bf16* __restrict__ bt,   // frag-ordered B tiles
              const __bf16* __restrict__ ra,   // ragged-A swz bf16 images
              const float* __restrict__ wpt,   // [V, C_TOT] transposed w'
              float* __restrict__ out)         // [B, V]
{
  __shared__ float lds_af[2 * TILE_E];   // 64 KB: double-buffered fp32 A

  const int tid  = threadIdx.x;
  const int lane = tid & 63;
  const int wid  = tid >> 6;
  const int wm   = wid >> 1;
  const int wn   = wid & 1;

  // XCD-interleaved, x-quad-preserving decode: 4 N-siblings of one A-panel
  // co-locate on an XCD; LPT order (long blocks first).
  const int bid   = blockIdx.x;
  const int sslot = bid >> 3;
  const int xcd   = bid & 7;
  const int w     = (((sslot >> 2) << 3) + xcd) * 4 + (sslot & 3);

  f32x4 acc[4][4];
#pragma unroll
  for (int i = 0; i < 4; ++i)
#pragma unroll
    for (int j = 0; j < 4; ++j)
      acc[i][j] = f32x4{0.f, 0.f, 0.f, 0.f};

  int Ck, Coff, bn_g, bn;
  long bm;

  // B fragment loads: frag-ordered tile -> 8 coalesced dwordx4 per wave
  auto load_b = [&](const __bf16* tbp, bf16x8* br) {
#pragma unroll
    for (int j = 0; j < 4; ++j)
#pragma unroll
      for (int kc = 0; kc < 2; ++kc)
        br[j * 2 + kc] = *(const bf16x8*)(
            tbp + ((((wn * 4 + j) * 2 + kc) << 6) + lane) * 8);
  };

  if (w < 2560) {
    // ======================= MAIN: fp32-A full steps =======================
    const float* fmap; int K, nst, bbase, y, s0k, nfull;
    if (w < 1024) {
      fmap = f0; K = 3136; nst = 49; bbase = 0; Ck = 64; Coff = 0;
      bn_g = w & 3; y = (w >> 2) & 63;
      const int z = w >> 8; s0k = z * 12; nfull = (z == 3) ? 13 : 12;
    } else if (w < 1536) {
      const int l = w - 1024;
      fmap = f1; K = 784; nst = 13; bbase = 196; Ck = 128; Coff = 64;
      bn_g = l & 3; y = l >> 2; s0k = 0; nfull = 12;
    } else {
      const int l = w - 1536;
      fmap = f2; K = 196; nst = 4; bbase = 248; Ck = 256; Coff = 192;
      bn_g = l & 3; y = l >> 2; s0k = 0; nfull = 3;
    }
    bm = (long)y * 128; bn = bn_g * 128;

    // stage raw fp32 A tile of step ks into buffer at elem-offset bo:
    // inverse-swizzled per-lane source, linear 16B/lane dest
    auto stage_a = [&](int bo, int ks) {
      const float* ab = fmap + bm * (long)K + (long)ks * 64;
#pragma unroll
      for (int i = 0; i < 8; ++i) {
        const int seg = wid * 8 + i;
        const int cc  = seg * 64 + lane;       // dest 16B-chunk 0..2047
        const int row = cc >> 4;
        const int q4  = (cc & 15) ^ (row & 7); // source 4-float chunk
        __builtin_amdgcn_global_load_lds(
            (const __attribute__((address_space(1))) void*)(ab + (long)row * K + q4 * 4),
            (__attribute__((address_space(3))) void*)(&lds_af[bo + seg * 256]),
            16, 0, 0);
      }
    };

    // prologue: issue stage(s0k) into buf0 (no wait yet)
    stage_a(0, s0k);

    for (int t = 0; t < nfull; ++t) {
      const int ks = s0k + t;
      const int ro = (t & 1) * TILE_E;
      const int wo = ((t + 1) & 1) * TILE_E;

      // B(t) -> regs FIRST (older than the prefetch in the vmcnt FIFO)
      bf16x8 breg[8];
      load_b(bt + (long)(bbase + bn_g * nst + ks) * TILE_E, breg);

      // prefetch A(t+1) into the buffer freed by the previous iteration's
      // trailing barrier; stays in flight across THIS barrier (counted wait)
      const bool pf = (t + 1 < nfull);
      if (pf) {
        stage_a(wo, ks + 1);
        asm volatile("s_waitcnt vmcnt(16)" ::: "memory");  // stage(t) landed;
      } else {                                             // B(t)+stage(t+1)
        asm volatile("s_waitcnt vmcnt(8)" ::: "memory");   // remain in flight
      }
      __builtin_amdgcn_sched_barrier(0);
      __builtin_amdgcn_s_barrier();          // all waves' stage(t) landed
      __builtin_amdgcn_sched_barrier(0);

      // compute(t): A = 2x ds_read_b128 fp32 + cast; B in regs
      __builtin_amdgcn_s_setprio(1);
#pragma unroll
      for (int kc = 0; kc < 2; ++kc) {
        const int q4a = kc * 8 + ((lane >> 4) << 1);
        bf16x8 af[4];
#pragma unroll
        for (int i = 0; i < 4; ++i) {
          const int r = wm * 64 + i * 16 + (lane & 15);
          const f32x4 fa = *(const f32x4*)&lds_af[ro + r * 64 + ((q4a ^ (r & 7)) << 2)];
          const f32x4 fb = *(const f32x4*)&lds_af[ro + r * 64 + (((q4a + 1) ^ (r & 7)) << 2)];
          af[i] = cvt8(fa, fb);
        }
#pragma unroll
        for (int i = 0; i < 4; ++i)
#pragma unroll
          for (int j = 0; j < 4; ++j)
            acc[i][j] = __builtin_amdgcn_mfma_f32_16x16x32_bf16(
                af[i], breg[j * 2 + kc], acc[i][j], 0, 0, 0);
      }
      __builtin_amdgcn_s_setprio(0);

      // free buf[ro] for the next iteration's prefetch (WAR guard)
      __builtin_amdgcn_sched_barrier(0);
      __builtin_amdgcn_s_barrier();
      __builtin_amdgcn_sched_barrier(0);
    }
  } else {
    // ================== TAIL: one bf16-image step per block =================
    const int l = w - 2560;
    int y, btile;
    long raidx;
    if (l < 512) {
      y = l >> 2; bn_g = l & 3; raidx = y;          Ck = 128; Coff = 64;
      btile = 196 + bn_g * 13 + 12;
    } else if (l < 1536) {
      const int m = l - 512;
      y = m >> 2; bn_g = m & 3; raidx = 128 + y;    Ck = 256; Coff = 192;
      btile = 248 + bn_g * 4 + 3;
    } else {
      const int m = l - 1536;
      y = m >> 2; bn_g = m & 3; raidx = 384 + y;    Ck = 512; Coff = 448;
      btile = 264 + bn_g;
    }
    bm = (long)y * 128; bn = bn_g * 128;

    __bf16* lds_ab = (__bf16*)lds_af;
    const __bf16* asrc = ra + raidx * TILE_E;
#pragma unroll
    for (int i = 0; i < 4; ++i) {
      const int seg = wid * 4 + i;
      __builtin_amdgcn_global_load_lds(
          (const __attribute__((address_space(1))) void*)(asrc + seg * 512 + lane * 8),
          (__attribute__((address_space(3))) void*)(&lds_ab[seg * 512]),
          16, 0, 0);
    }
    bf16x8 breg[8];
    load_b(bt + (long)btile * TILE_E, breg);
    __syncthreads();

#pragma unroll
    for (int kc = 0; kc < 2; ++kc) {
      const int cx = kc * 4 + (lane >> 4);
      bf16x8 af[4];
#pragma unroll
      for (int i = 0; i < 4; ++i) {
        const int r = wm * 64 + i * 16 + (lane & 15);
        af[i] = *(const bf16x8*)&lds_ab[r * 64 + ((cx ^ (r & 7)) << 3)];
      }
#pragma unroll
      for (int i = 0; i < 4; ++i)
#pragma unroll
        for (int j = 0; j < 4; ++j)
          acc[i][j] = __builtin_amdgcn_mfma_f32_16x16x32_bf16(
              af[i], breg[j * 2 + kc], acc[i][j], 0, 0, 0);
    }
  }

  // ---- epilogue: per-wave 64x64 feats sub-tile, c-reduce, atomicAdd.
  // C/D layout: frag row = (lane>>4)*4 + reg, frag col = lane&15   [m89]
  const long mbase = bm + wm * 64;
  const int  bidx  = (int)(mbase / Ck);
  const int  cbase = (int)(mbase % Ck) + Coff;
  const int  lcol  = lane & 15;

#pragma unroll
  for (int j = 0; j < 4; ++j) {
    const int v = bn + wn * 64 + j * 16 + lcol;
    float s = 0.f;
#pragma unroll
    for (int i = 0; i < 4; ++i) {
      const int cg = cbase + i * 16 + ((lane >> 4) << 2);
      const f32x4 w4 = *(const f32x4*)&wpt[(long)v * C_TOT + cg];
      s += acc[i][j][0] * w4[0] + acc[i][j][1] * w4[1]
         + acc[i][j][2] * w4[2] + acc[i][j][3] * w4[3];
    }
    s += __shfl_xor(s, 16);
    s += __shfl_xor(s, 32);
    if (lane < 16)
      atomicAdd(&out[(long)bidx * V_DIM + v], s);
  }
}

// ---------------------------------------------------------------------------
// Ragged-A image convert: img[swz_idx(row,k)] = src[rbase+row, ks*64+k],
// zero-padded past K.
// ---------------------------------------------------------------------------
static __device__ __forceinline__ void conv_tile(const float* __restrict__ src,
                                                 int K, long rbase, int ks,
                                                 __bf16* __restrict__ dst, int tid)
{
#pragma unroll
  for (int it = 0; it < 4; ++it) {
    const int u   = tid + it * 256;
    const int row = u >> 3;
    const int q8  = u & 7;
    const int k   = ((q8 ^ (row & 7)) << 3);
    const long gk = (long)ks * 64 + k;
    const float* sp = src + (rbase + row) * (long)K + gk;
    bf16x8 h;
    if (gk + 8 <= K) {
      h = cvt8(*(const f32x4u*)sp, *(const f32x4u*)(sp + 4));
    } else {
#pragma unroll
      for (int e = 0; e < 8; ++e)
        h[e] = (__bf16)((gk + e < K) ? sp[e] : 0.f);
    }
    *(bf16x8*)&dst[(long)row * 64 + q8 * 8] = h;
  }
}

// ---------------------------------------------------------------------------
// One prep launch: [0,268) B frag-ordered tiles; [268,1164) ragged-A images;
// then wpt (v-major w'); then out init with the constant term.
// B tile layout: dst[((fj*2+kc)*64 + l)*8 + e] =
//   B[g*128 + fj*16 + (l&15), ks*64 + kc*32 + ((l>>4)<<3) + e]  (0-padded)
// ---------------------------------------------------------------------------
__global__ void prep_all(const float* __restrict__ f1, const float* __restrict__ f2,
                         const float* __restrict__ f3,
                         const float* __restrict__ p0, const float* __restrict__ p1,
                         const float* __restrict__ p2, const float* __restrict__ p3,
                         const float* __restrict__ weights,
                         const float* __restrict__ bias,
                         const float* __restrict__ fm,
                         const float* __restrict__ fs,
                         float* __restrict__ wpt,     // may be null
                         __bf16* __restrict__ bt,     // may be null
                         __bf16* __restrict__ ra,     // may be null
                         float* __restrict__ out)
{
  __shared__ float red[4];
  const int blk = blockIdx.x;
  const int tid = threadIdx.x;

  if (blk < NBT) {
    if (!bt) return;
    int t = blk; const float* src; int K, g, ks;
    if (t < 196)      { src = p0; K = 3136; g = t / 49; ks = t % 49; }
    else if (t < 248) { t -= 196; src = p1; K = 784; g = t / 13; ks = t % 13; }
    else if (t < 264) { t -= 248; src = p2; K = 196; g = t / 4;  ks = t % 4; }
    else              { t -= 264; src = p3; K = 49;  g = t;      ks = 0; }
    __bf16* dst = bt + (long)blk * TILE_E;
#pragma unroll
    for (int it = 0; it < 4; ++it) {
      const int c2 = tid + it * 256;
      const int fj = c2 >> 7;
      const int kc = (c2 >> 6) & 1;
      const int l  = c2 & 63;
      const int row  = g * 128 + fj * 16 + (l & 15);
      const int kcol = ks * 64 + kc * 32 + ((l >> 4) << 3);
      const float* sp = src + (long)row * K + kcol;
      bf16x8 h;
      if (kcol + 8 <= K) {
        h = cvt8(*(const f32x4u*)sp, *(const f32x4u*)(sp + 4));
      } else {
#pragma unroll
        for (int e = 0; e < 8; ++e)
          h[e] = (__bf16)((kcol + e < K) ? sp[e] : 0.f);
      }
      *(bf16x8*)&dst[(long)c2 * 8] = h;
    }
  } else if (blk < NBT + NRA) {
    if (!ra) return;
    const int t = blk - NBT; const float* src; int K, ks; long rbase;
    if (t < 128)      { src = f1; K = 784; ks = 12; rbase = (long)t * 128; }
    else if (t < 384) { src = f2; K = 196; ks = 3;  rbase = (long)(t - 128) * 128; }
    else              { src = f3; K = 49;  ks = 0;  rbase = (long)(t - 384) * 128; }
    conv_tile(src, K, rbase, ks, ra + (long)t * TILE_E, tid);
  } else if (blk < NBT + NRA + PREP_WP) {
    if (!wpt) return;
    const int idx = (blk - NBT - NRA) * 256 + tid;   // exactly 960*512
    const int v = idx / C_TOT;
    const int c = idx - v * C_TOT;
    wpt[idx] = weights[idx] / fs[(long)c * V_DIM + v];   // wpt layout == weights
  } else {
    const int v = blk - (NBT + NRA + PREP_WP);       // 0..511
    float s = 0.f;
    for (int c = tid; c < C_TOT; c += 256) {
      const long i = (long)c * V_DIM + v;
      s += fm[i] * weights[(long)v * C_TOT + c] / fs[i];
    }
#pragma unroll
    for (int o = 32; o; o >>= 1) s += __shfl_down(s, o);
    if ((tid & 63) == 0) red[tid >> 6] = s;
    __syncthreads();
    if (tid < B_DIM) {
      const float off = bias[v] - (red[0] + red[1] + red[2] + red[3]);
      out[(long)tid * V_DIM + v] = off;
    }
  }
}

// ---------------------------------------------------------------------------
// Fallback GEMM (ws too small): inline fp32 staging of both operands.
// ---------------------------------------------------------------------------
__global__ __launch_bounds__(256, 3)
void gemm_fb(const float* __restrict__ fmap, const float* __restrict__ prf,
             const float* __restrict__ weights, const float* __restrict__ fs,
             float* __restrict__ out,
             int Ck, int K, int Coff, int nsteps, int kchunks)
{
  __shared__ __bf16 lds_a[TILE_E];
  __shared__ __bf16 lds_b[TILE_E];
  const int tid = threadIdx.x, lane = tid & 63, wid = tid >> 6;
  const int wm = wid >> 1, wn = wid & 1;
  const long bm = (long)blockIdx.y * 128;
  const int bn = blockIdx.x * 128;
  const int z = blockIdx.z, qb = nsteps / kchunks, rb = nsteps % kchunks;
  const int s0 = z * qb + (z < rb ? z : rb);
  const int send = s0 + qb + (z < rb ? 1 : 0);

  f32x4 acc[4][4];
#pragma unroll
  for (int i = 0; i < 4; ++i)
#pragma unroll
    for (int j = 0; j < 4; ++j) acc[i][j] = f32x4{0.f, 0.f, 0.f, 0.f};

  for (int ks = s0; ks < send; ++ks) {
    __syncthreads();
#pragma unroll
    for (int i = 0; i < 8; ++i) {
      const int c = tid + i * 256, row = c >> 4, k0 = (c & 15) << 2;
      const long gk = (long)ks * 64 + k0;
      const float* ap = fmap + (bm + row) * (long)K + gk;
      const float* bp = prf + (long)(bn + row) * K + gk;
      float a[4], b[4];
#pragma unroll
      for (int e = 0; e < 4; ++e) {
        a[e] = (gk + e < K) ? ap[e] : 0.f;
        b[e] = (gk + e < K) ? bp[e] : 0.f;
      }
      bf16x4 ha = {(__bf16)a[0], (__bf16)a[1], (__bf16)a[2], (__bf16)a[3]};
      bf16x4 hb = {(__bf16)b[0], (__bf16)b[1], (__bf16)b[2], (__bf16)b[3]};
      *(bf16x4*)&lds_a[swz_idx(row, k0)] = ha;
      *(bf16x4*)&lds_b[swz_idx(row, k0)] = hb;
    }
    __syncthreads();
#pragma unroll
    for (int kc = 0; kc < 2; ++kc) {
      const int cx = kc * 4 + (lane >> 4);
      bf16x8 af[4], bfr[4];
#pragma unroll
      for (int i = 0; i < 4; ++i) {
        const int r = wm * 64 + i * 16 + (lane & 15);
        af[i] = *(const bf16x8*)&lds_a[r * 64 + ((cx ^ (r & 7)) << 3)];
      }
#pragma unroll
      for (int j = 0; j < 4; ++j) {
        const int r = wn * 64 + j * 16 + (lane & 15);
        bfr[j] = *(const bf16x8*)&lds_b[r * 64 + ((cx ^ (r & 7)) << 3)];
      }
#pragma unroll
      for (int i = 0; i < 4; ++i)
#pragma unroll
        for (int j = 0; j < 4; ++j)
          acc[i][j] = __builtin_amdgcn_mfma_f32_16x16x32_bf16(af[i], bfr[j],
                                                              acc[i][j], 0, 0, 0);
    }
  }

  const long mbase = bm + wm * 64;
  const int bidx = (int)(mbase / Ck);
  const int cbase = (int)(mbase % Ck) + Coff;
  const int lrow = ((lane >> 4) << 2), lcol = lane & 15;
#pragma unroll
  for (int j = 0; j < 4; ++j) {
    const int v = bn + wn * 64 + j * 16 + lcol;
    float s = 0.f;
#pragma unroll
    for (int i = 0; i < 4; ++i) {
      const int cg = cbase + i * 16 + lrow;
#pragma unroll
      for (int r = 0; r < 4; ++r) {
        const float wf = weights[(long)v * C_TOT + cg + r]
                         / fs[(long)(cg + r) * V_DIM + v];
        s += acc[i][j][r] * wf;
      }
    }
    s += __shfl_xor(s, 16);
    s += __shfl_xor(s, 32);
    if (lane < 16) atomicAdd(&out[(long)bidx * V_DIM + v], s);
  }
}

extern "C" void kernel_launch(void* const* d_in, const int* in_sizes, int n_in,
                              void* d_out, int out_size, void* d_ws, size_t ws_size,
                              hipStream_t stream)
{
  const float* fmap0   = (const float*)d_in[0];
  const float* prf0    = (const float*)d_in[1];
  const float* fmap1   = (const float*)d_in[2];
  const float* prf1    = (const float*)d_in[3];
  const float* fmap2   = (const float*)d_in[4];
  const float* prf2    = (const float*)d_in[5];
  const float* fmap3   = (const float*)d_in[6];
  const float* prf3    = (const float*)d_in[7];
  const float* weights = (const float*)d_in[8];
  const float* bias    = (const float*)d_in[9];
  const float* fm      = (const float*)d_in[10];
  const float* fs      = (const float*)d_in[11];
  float* out = (float*)d_out;

  const bool has_ws = ws_size >= (size_t)WS_NEED;
  float*  wpt = has_ws ? (float*)d_ws : nullptr;
  __bf16* bt  = has_ws ? (__bf16*)((char*)d_ws + WP_BYTES) : nullptr;
  __bf16* ra  = has_ws ? (__bf16*)((char*)d_ws + WP_BYTES + BT_BYTES) : nullptr;

  // 1) prep: B frag tiles + ragged-A images + wpt + out init
  prep_all<<<dim3(PREP_BLKS), dim3(256), 0, stream>>>(
      fmap1, fmap2, fmap3, prf0, prf1, prf2, prf3,
      weights, bias, fm, fs, wpt, bt, ra, out);

  // 2) GEMM
  if (has_ws) {
    gemm_all<<<dim3(GEMM_BLKS), dim3(256), 0, stream>>>(
        fmap0, fmap1, fmap2, bt, ra, wpt, out);
  } else {
    struct Scale { const float* fmap; const float* prf; int Ck, K, Coff, nst, kch; };
    const Scale sc[4] = {
      {fmap0, prf0,  64, 3136,   0, 49, 4},
      {fmap1, prf1, 128,  784,  64, 13, 2},
      {fmap2, prf2, 256,  196, 192,  4, 1},
      {fmap3, prf3, 512,   49, 448,  1, 1},
    };
    for (int k = 0; k < 4; ++k) {
      dim3 grid(4, B_DIM * sc[k].Ck / 128, sc[k].kch);
      gemm_fb<<<grid, dim3(256), 0, stream>>>(
          sc[k].fmap, sc[k].prf, weights, fs, out,
          sc[k].Ck, sc[k].K, sc[k].Coff, sc[k].nst, sc[k].kch);
    }
  }
}

// Round 14
// 128.699 us; speedup vs baseline: 1.1312x; 1.0745x over previous
//
#include <hip/hip_runtime.h>

// ---------------------------------------------------------------------------
// r[b,v] = sum_c (feats[b,c,v] - m[c,v]) / s[c,v] * weights[v,c] + bias[v]
// feats per scale k: GEMM  fmap_k (B*Ck x K=n^2)  @  prf_k^T (K x V)
// Fused epilogue: feats tile * w'[c,v], c-reduced, atomicAdd into out
// (pre-initialized with off[v] = bias - sum m*w').
//
// R13 = EXACT R8 loop (single 32KB fp32-A buffer via global_load_lds,
// 2 __syncthreads per step -- the proven-best structure, 110us) with ONE
// delta: B fragments direct-to-register from frag-ordered bf16 ws tiles
// (no lds_b). At 88 VGPR (R12-measured, no spill under (256,2)) and 32KB
// LDS the occupancy cap rises 3 -> 5 blocks/CU; per-step LDS traffic drops
// 144 -> 96KB. R11's version of this was poisoned by (256,4) VGPR spill.
// ---------------------------------------------------------------------------

typedef float f32x4 __attribute__((ext_vector_type(4)));
typedef f32x4 __attribute__((aligned(4))) f32x4u;
typedef __bf16 bf16x4 __attribute__((ext_vector_type(4)));
typedef __bf16 bf16x8 __attribute__((ext_vector_type(8)));

#define TILE_E 8192              // elems per [128x64] tile
#define V_DIM 512
#define C_TOT 960
#define B_DIM 128

#define NBT 268                  // B tiles: 4 col-groups x (49+13+4+1)
#define NRA 896                  // ragged-A images: 128(s1)+256(s2)+512(s3)
#define PREP_WP 1920
#define PREP_OFF 512
#define PREP_BLKS (NBT + NRA + PREP_WP + PREP_OFF)

#define GEMM_BLKS 6144           // 1024(s0)+512(s1)+1024(s2)+3584(tail) = 8*768

// workspace layout (bytes): [wpt][bt][ra]
#define WP_BYTES 1966080L                   // 960*512*4 (v-major)
#define BT_BYTES ((long)NBT * TILE_E * 2)   // 4,390,912
#define RA_BYTES ((long)NRA * TILE_E * 2)   // 14,680,064
#define WS_NEED  (WP_BYTES + BT_BYTES + RA_BYTES)

static __device__ __forceinline__ bf16x8 cvt8(f32x4 lo, f32x4 hi) {
  return bf16x8{(__bf16)lo[0], (__bf16)lo[1], (__bf16)lo[2], (__bf16)lo[3],
                (__bf16)hi[0], (__bf16)hi[1], (__bf16)hi[2], (__bf16)hi[3]};
}

// T2 XOR-swizzle, 16B granularity, inside a [128][64]-elem bf16 tile
static __device__ __forceinline__ int swz_idx(int row, int k) {
  return row * 64 + (((k >> 3) ^ (row & 7)) << 3) + (k & 7);
}

// ---------------------------------------------------------------------------
// Fused GEMM, single launch (requires ws). Decode after XCD interleave:
//   w in [0,1024): s0 full steps, split-K x4
//   w in [1024,1536): s1 full steps 0..11
//   w in [1536,2560): s2 full steps 0..2
//   w in [2560,6144): tail (1 bf16-image step): s1@12, s2@3, s3@0
// ---------------------------------------------------------------------------
__global__ __launch_bounds__(256, 2)
void gemm_all(const float* __restrict__ f0, const float* __restrict__ f1,
              const float* __restrict__ f2,
              const __bf16* __restrict__ bt,   // frag-ordered B tiles
              const __bf16* __restrict__ ra,   // ragged-A swz bf16 images
              const float* __restrict__ wpt,   // [V, C_TOT] transposed w'
              float* __restrict__ out)         // [B, V]
{
  __shared__ float lds_af[TILE_E];   // 32 KB fp32 A (tail reuses as bf16)

  const int tid  = threadIdx.x;
  const int lane = tid & 63;
  const int wid  = tid >> 6;
  const int wm   = wid >> 1;
  const int wn   = wid & 1;

  // XCD-interleaved, x-quad-preserving decode: 4 N-siblings of one A-panel
  // co-locate on an XCD; LPT order (long blocks first).
  const int bid   = blockIdx.x;
  const int sslot = bid >> 3;
  const int xcd   = bid & 7;
  const int w     = (((sslot >> 2) << 3) + xcd) * 4 + (sslot & 3);

  f32x4 acc[4][4];
#pragma unroll
  for (int i = 0; i < 4; ++i)
#pragma unroll
    for (int j = 0; j < 4; ++j)
      acc[i][j] = f32x4{0.f, 0.f, 0.f, 0.f};

  int Ck, Coff, bn_g, bn;
  long bm;

  // B fragment loads: frag-ordered tile -> 8 coalesced dwordx4 per wave
  auto load_b = [&](const __bf16* tbp, bf16x8* br) {
#pragma unroll
    for (int j = 0; j < 4; ++j)
#pragma unroll
      for (int kc = 0; kc < 2; ++kc)
        br[j * 2 + kc] = *(const bf16x8*)(
            tbp + ((((wn * 4 + j) * 2 + kc) << 6) + lane) * 8);
  };

  if (w < 2560) {
    // ======================= MAIN: fp32-A full steps =======================
    const float* fmap; int K, nst, bbase, y, s0k, sendk;
    if (w < 1024) {
      fmap = f0; K = 3136; nst = 49; bbase = 0; Ck = 64; Coff = 0;
      bn_g = w & 3; y = (w >> 2) & 63;
      const int z = w >> 8; s0k = z * 12; sendk = (z == 3) ? 49 : s0k + 12;
    } else if (w < 1536) {
      const int l = w - 1024;
      fmap = f1; K = 784; nst = 13; bbase = 196; Ck = 128; Coff = 64;
      bn_g = l & 3; y = l >> 2; s0k = 0; sendk = 12;
    } else {
      const int l = w - 1536;
      fmap = f2; K = 196; nst = 4; bbase = 248; Ck = 256; Coff = 192;
      bn_g = l & 3; y = l >> 2; s0k = 0; sendk = 3;
    }
    bm = (long)y * 128; bn = bn_g * 128;

    for (int ks = s0k; ks < sendk; ++ks) {
      __syncthreads();   // previous step's LDS readers done

      // stage A: raw fp32, inverse-swizzled per-lane source, linear dest
      const float* ab = fmap + bm * (long)K + (long)ks * 64;
#pragma unroll
      for (int i = 0; i < 8; ++i) {
        const int seg = wid * 8 + i;
        const int cc  = seg * 64 + lane;       // dest 16B-chunk 0..2047
        const int row = cc >> 4;
        const int q4  = (cc & 15) ^ (row & 7); // source 4-float chunk
        __builtin_amdgcn_global_load_lds(
            (const __attribute__((address_space(1))) void*)(ab + (long)row * K + q4 * 4),
            (__attribute__((address_space(3))) void*)(&lds_af[seg * 256]),
            16, 0, 0);
      }
      // B fragments -> regs (drained together with the stage at sync2)
      bf16x8 breg[8];
      load_b(bt + (long)(bbase + bn_g * nst + ks) * TILE_E, breg);

      __syncthreads();   // drains gl_lds + breg (vmcnt 0)

      // fragments: A = 2x ds_read_b128 fp32 + cast; B already in regs
      __builtin_amdgcn_s_setprio(1);
#pragma unroll
      for (int kc = 0; kc < 2; ++kc) {
        const int q4a = kc * 8 + ((lane >> 4) << 1);
        bf16x8 af[4];
#pragma unroll
        for (int i = 0; i < 4; ++i) {
          const int r = wm * 64 + i * 16 + (lane & 15);
          const f32x4 fa = *(const f32x4*)&lds_af[r * 64 + ((q4a ^ (r & 7)) << 2)];
          const f32x4 fb = *(const f32x4*)&lds_af[r * 64 + (((q4a + 1) ^ (r & 7)) << 2)];
          af[i] = cvt8(fa, fb);
        }
#pragma unroll
        for (int i = 0; i < 4; ++i)
#pragma unroll
          for (int j = 0; j < 4; ++j)
            acc[i][j] = __builtin_amdgcn_mfma_f32_16x16x32_bf16(
                af[i], breg[j * 2 + kc], acc[i][j], 0, 0, 0);
      }
      __builtin_amdgcn_s_setprio(0);
    }
  } else {
    // ================== TAIL: one bf16-image step per block =================
    const int l = w - 2560;
    int y, btile;
    long raidx;
    if (l < 512) {
      y = l >> 2; bn_g = l & 3; raidx = y;          Ck = 128; Coff = 64;
      btile = 196 + bn_g * 13 + 12;
    } else if (l < 1536) {
      const int m = l - 512;
      y = m >> 2; bn_g = m & 3; raidx = 128 + y;    Ck = 256; Coff = 192;
      btile = 248 + bn_g * 4 + 3;
    } else {
      const int m = l - 1536;
      y = m >> 2; bn_g = m & 3; raidx = 384 + y;    Ck = 512; Coff = 448;
      btile = 264 + bn_g;
    }
    bm = (long)y * 128; bn = bn_g * 128;

    __bf16* lds_ab = (__bf16*)lds_af;
    const __bf16* asrc = ra + raidx * TILE_E;
#pragma unroll
    for (int i = 0; i < 4; ++i) {
      const int seg = wid * 4 + i;
      __builtin_amdgcn_global_load_lds(
          (const __attribute__((address_space(1))) void*)(asrc + seg * 512 + lane * 8),
          (__attribute__((address_space(3))) void*)(&lds_ab[seg * 512]),
          16, 0, 0);
    }
    bf16x8 breg[8];
    load_b(bt + (long)btile * TILE_E, breg);
    __syncthreads();

#pragma unroll
    for (int kc = 0; kc < 2; ++kc) {
      const int cx = kc * 4 + (lane >> 4);
      bf16x8 af[4];
#pragma unroll
      for (int i = 0; i < 4; ++i) {
        const int r = wm * 64 + i * 16 + (lane & 15);
        af[i] = *(const bf16x8*)&lds_ab[r * 64 + ((cx ^ (r & 7)) << 3)];
      }
#pragma unroll
      for (int i = 0; i < 4; ++i)
#pragma unroll
        for (int j = 0; j < 4; ++j)
          acc[i][j] = __builtin_amdgcn_mfma_f32_16x16x32_bf16(
              af[i], breg[j * 2 + kc], acc[i][j], 0, 0, 0);
    }
  }

  // ---- epilogue: per-wave 64x64 feats sub-tile, c-reduce, atomicAdd.
  // C/D layout: frag row = (lane>>4)*4 + reg, frag col = lane&15   [m89]
  const long mbase = bm + wm * 64;
  const int  bidx  = (int)(mbase / Ck);
  const int  cbase = (int)(mbase % Ck) + Coff;
  const int  lcol  = lane & 15;

#pragma unroll
  for (int j = 0; j < 4; ++j) {
    const int v = bn + wn * 64 + j * 16 + lcol;
    float s = 0.f;
#pragma unroll
    for (int i = 0; i < 4; ++i) {
      const int cg = cbase + i * 16 + ((lane >> 4) << 2);
      const f32x4 w4 = *(const f32x4*)&wpt[(long)v * C_TOT + cg];
      s += acc[i][j][0] * w4[0] + acc[i][j][1] * w4[1]
         + acc[i][j][2] * w4[2] + acc[i][j][3] * w4[3];
    }
    s += __shfl_xor(s, 16);
    s += __shfl_xor(s, 32);
    if (lane < 16)
      atomicAdd(&out[(long)bidx * V_DIM + v], s);
  }
}

// ---------------------------------------------------------------------------
// Ragged-A image convert: img[swz_idx(row,k)] = src[rbase+row, ks*64+k],
// zero-padded past K.
// ---------------------------------------------------------------------------
static __device__ __forceinline__ void conv_tile(const float* __restrict__ src,
                                                 int K, long rbase, int ks,
                                                 __bf16* __restrict__ dst, int tid)
{
#pragma unroll
  for (int it = 0; it < 4; ++it) {
    const int u   = tid + it * 256;
    const int row = u >> 3;
    const int q8  = u & 7;
    const int k   = ((q8 ^ (row & 7)) << 3);
    const long gk = (long)ks * 64 + k;
    const float* sp = src + (rbase + row) * (long)K + gk;
    bf16x8 h;
    if (gk + 8 <= K) {
      h = cvt8(*(const f32x4u*)sp, *(const f32x4u*)(sp + 4));
    } else {
#pragma unroll
      for (int e = 0; e < 8; ++e)
        h[e] = (__bf16)((gk + e < K) ? sp[e] : 0.f);
    }
    *(bf16x8*)&dst[(long)row * 64 + q8 * 8] = h;
  }
}

// ---------------------------------------------------------------------------
// One prep launch: [0,268) B frag-ordered tiles; [268,1164) ragged-A images;
// then wpt (v-major w'); then out init with the constant term.
// B tile layout: dst[((fj*2+kc)*64 + l)*8 + e] =
//   B[g*128 + fj*16 + (l&15), ks*64 + kc*32 + ((l>>4)<<3) + e]  (0-padded)
// ---------------------------------------------------------------------------
__global__ void prep_all(const float* __restrict__ f1, const float* __restrict__ f2,
                         const float* __restrict__ f3,
                         const float* __restrict__ p0, const float* __restrict__ p1,
                         const float* __restrict__ p2, const float* __restrict__ p3,
                         const float* __restrict__ weights,
                         const float* __restrict__ bias,
                         const float* __restrict__ fm,
                         const float* __restrict__ fs,
                         float* __restrict__ wpt,     // may be null
                         __bf16* __restrict__ bt,     // may be null
                         __bf16* __restrict__ ra,     // may be null
                         float* __restrict__ out)
{
  __shared__ float red[4];
  const int blk = blockIdx.x;
  const int tid = threadIdx.x;

  if (blk < NBT) {
    if (!bt) return;
    int t = blk; const float* src; int K, g, ks;
    if (t < 196)      { src = p0; K = 3136; g = t / 49; ks = t % 49; }
    else if (t < 248) { t -= 196; src = p1; K = 784; g = t / 13; ks = t % 13; }
    else if (t < 264) { t -= 248; src = p2; K = 196; g = t / 4;  ks = t % 4; }
    else              { t -= 264; src = p3; K = 49;  g = t;      ks = 0; }
    __bf16* dst = bt + (long)blk * TILE_E;
#pragma unroll
    for (int it = 0; it < 4; ++it) {
      const int c2 = tid + it * 256;
      const int fj = c2 >> 7;
      const int kc = (c2 >> 6) & 1;
      const int l  = c2 & 63;
      const int row  = g * 128 + fj * 16 + (l & 15);
      const int kcol = ks * 64 + kc * 32 + ((l >> 4) << 3);
      const float* sp = src + (long)row * K + kcol;
      bf16x8 h;
      if (kcol + 8 <= K) {
        h = cvt8(*(const f32x4u*)sp, *(const f32x4u*)(sp + 4));
      } else {
#pragma unroll
        for (int e = 0; e < 8; ++e)
          h[e] = (__bf16)((kcol + e < K) ? sp[e] : 0.f);
      }
      *(bf16x8*)&dst[(long)c2 * 8] = h;
    }
  } else if (blk < NBT + NRA) {
    if (!ra) return;
    const int t = blk - NBT; const float* src; int K, ks; long rbase;
    if (t < 128)      { src = f1; K = 784; ks = 12; rbase = (long)t * 128; }
    else if (t < 384) { src = f2; K = 196; ks = 3;  rbase = (long)(t - 128) * 128; }
    else              { src = f3; K = 49;  ks = 0;  rbase = (long)(t - 384) * 128; }
    conv_tile(src, K, rbase, ks, ra + (long)t * TILE_E, tid);
  } else if (blk < NBT + NRA + PREP_WP) {
    if (!wpt) return;
    const int idx = (blk - NBT - NRA) * 256 + tid;   // exactly 960*512
    const int v = idx / C_TOT;
    const int c = idx - v * C_TOT;
    wpt[idx] = weights[idx] / fs[(long)c * V_DIM + v];   // wpt layout == weights
  } else {
    const int v = blk - (NBT + NRA + PREP_WP);       // 0..511
    float s = 0.f;
    for (int c = tid; c < C_TOT; c += 256) {
      const long i = (long)c * V_DIM + v;
      s += fm[i] * weights[(long)v * C_TOT + c] / fs[i];
    }
#pragma unroll
    for (int o = 32; o; o >>= 1) s += __shfl_down(s, o);
    if ((tid & 63) == 0) red[tid >> 6] = s;
    __syncthreads();
    if (tid < B_DIM) {
      const float off = bias[v] - (red[0] + red[1] + red[2] + red[3]);
      out[(long)tid * V_DIM + v] = off;
    }
  }
}

// ---------------------------------------------------------------------------
// Fallback GEMM (ws too small): inline fp32 staging of both operands.
// ---------------------------------------------------------------------------
__global__ __launch_bounds__(256, 3)
void gemm_fb(const float* __restrict__ fmap, const float* __restrict__ prf,
             const float* __restrict__ weights, const float* __restrict__ fs,
             float* __restrict__ out,
             int Ck, int K, int Coff, int nsteps, int kchunks)
{
  __shared__ __bf16 lds_a[TILE_E];
  __shared__ __bf16 lds_b[TILE_E];
  const int tid = threadIdx.x, lane = tid & 63, wid = tid >> 6;
  const int wm = wid >> 1, wn = wid & 1;
  const long bm = (long)blockIdx.y * 128;
  const int bn = blockIdx.x * 128;
  const int z = blockIdx.z, qb = nsteps / kchunks, rb = nsteps % kchunks;
  const int s0 = z * qb + (z < rb ? z : rb);
  const int send = s0 + qb + (z < rb ? 1 : 0);

  f32x4 acc[4][4];
#pragma unroll
  for (int i = 0; i < 4; ++i)
#pragma unroll
    for (int j = 0; j < 4; ++j) acc[i][j] = f32x4{0.f, 0.f, 0.f, 0.f};

  for (int ks = s0; ks < send; ++ks) {
    __syncthreads();
#pragma unroll
    for (int i = 0; i < 8; ++i) {
      const int c = tid + i * 256, row = c >> 4, k0 = (c & 15) << 2;
      const long gk = (long)ks * 64 + k0;
      const float* ap = fmap + (bm + row) * (long)K + gk;
      const float* bp = prf + (long)(bn + row) * K + gk;
      float a[4], b[4];
#pragma unroll
      for (int e = 0; e < 4; ++e) {
        a[e] = (gk + e < K) ? ap[e] : 0.f;
        b[e] = (gk + e < K) ? bp[e] : 0.f;
      }
      bf16x4 ha = {(__bf16)a[0], (__bf16)a[1], (__bf16)a[2], (__bf16)a[3]};
      bf16x4 hb = {(__bf16)b[0], (__bf16)b[1], (__bf16)b[2], (__bf16)b[3]};
      *(bf16x4*)&lds_a[swz_idx(row, k0)] = ha;
      *(bf16x4*)&lds_b[swz_idx(row, k0)] = hb;
    }
    __syncthreads();
#pragma unroll
    for (int kc = 0; kc < 2; ++kc) {
      const int cx = kc * 4 + (lane >> 4);
      bf16x8 af[4], bfr[4];
#pragma unroll
      for (int i = 0; i < 4; ++i) {
        const int r = wm * 64 + i * 16 + (lane & 15);
        af[i] = *(const bf16x8*)&lds_a[r * 64 + ((cx ^ (r & 7)) << 3)];
      }
#pragma unroll
      for (int j = 0; j < 4; ++j) {
        const int r = wn * 64 + j * 16 + (lane & 15);
        bfr[j] = *(const bf16x8*)&lds_b[r * 64 + ((cx ^ (r & 7)) << 3)];
      }
#pragma unroll
      for (int i = 0; i < 4; ++i)
#pragma unroll
        for (int j = 0; j < 4; ++j)
          acc[i][j] = __builtin_amdgcn_mfma_f32_16x16x32_bf16(af[i], bfr[j],
                                                              acc[i][j], 0, 0, 0);
    }
  }

  const long mbase = bm + wm * 64;
  const int bidx = (int)(mbase / Ck);
  const int cbase = (int)(mbase % Ck) + Coff;
  const int lrow = ((lane >> 4) << 2), lcol = lane & 15;
#pragma unroll
  for (int j = 0; j < 4; ++j) {
    const int v = bn + wn * 64 + j * 16 + lcol;
    float s = 0.f;
#pragma unroll
    for (int i = 0; i < 4; ++i) {
      const int cg = cbase + i * 16 + lrow;
#pragma unroll
      for (int r = 0; r < 4; ++r) {
        const float wf = weights[(long)v * C_TOT + cg + r]
                         / fs[(long)(cg + r) * V_DIM + v];
        s += acc[i][j][r] * wf;
      }
    }
    s += __shfl_xor(s, 16);
    s += __shfl_xor(s, 32);
    if (lane < 16) atomicAdd(&out[(long)bidx * V_DIM + v], s);
  }
}

extern "C" void kernel_launch(void* const* d_in, const int* in_sizes, int n_in,
                              void* d_out, int out_size, void* d_ws, size_t ws_size,
                              hipStream_t stream)
{
  const float* fmap0   = (const float*)d_in[0];
  const float* prf0    = (const float*)d_in[1];
  const float* fmap1   = (const float*)d_in[2];
  const float* prf1    = (const float*)d_in[3];
  const float* fmap2   = (const float*)d_in[4];
  const float* prf2    = (const float*)d_in[5];
  const float* fmap3   = (const float*)d_in[6];
  const float* prf3    = (const float*)d_in[7];
  const float* weights = (const float*)d_in[8];
  const float* bias    = (const float*)d_in[9];
  const float* fm      = (const float*)d_in[10];
  const float* fs      = (const float*)d_in[11];
  float* out = (float*)d_out;

  const bool has_ws = ws_size >= (size_t)WS_NEED;
  float*  wpt = has_ws ? (float*)d_ws : nullptr;
  __bf16* bt  = has_ws ? (__bf16*)((char*)d_ws + WP_BYTES) : nullptr;
  __bf16* ra  = has_ws ? (__bf16*)((char*)d_ws + WP_BYTES + BT_BYTES) : nullptr;

  // 1) prep: B frag tiles + ragged-A images + wpt + out init
  prep_all<<<dim3(PREP_BLKS), dim3(256), 0, stream>>>(
      fmap1, fmap2, fmap3, prf0, prf1, prf2, prf3,
      weights, bias, fm, fs, wpt, bt, ra, out);

  // 2) GEMM
  if (has_ws) {
    gemm_all<<<dim3(GEMM_BLKS), dim3(256), 0, stream>>>(
        fmap0, fmap1, fmap2, bt, ra, wpt, out);
  } else {
    struct Scale { const float* fmap; const float* prf; int Ck, K, Coff, nst, kch; };
    const Scale sc[4] = {
      {fmap0, prf0,  64, 3136,   0, 49, 4},
      {fmap1, prf1, 128,  784,  64, 13, 2},
      {fmap2, prf2, 256,  196, 192,  4, 1},
      {fmap3, prf3, 512,   49, 448,  1, 1},
    };
    for (int k = 0; k < 4; ++k) {
      dim3 grid(4, B_DIM * sc[k].Ck / 128, sc[k].kch);
      gemm_fb<<<grid, dim3(256), 0, stream>>>(
          sc[k].fmap, sc[k].prf, weights, fs, out,
          sc[k].Ck, sc[k].K, sc[k].Coff, sc[k].nst, sc[k].kch);
    }
  }
}

// Round 15
// 123.759 us; speedup vs baseline: 1.1764x; 1.0399x over previous
//
#include <hip/hip_runtime.h>

// ---------------------------------------------------------------------------
// r[b,v] = sum_c (feats[b,c,v] - m[c,v]) / s[c,v] * weights[v,c] + bias[v]
// feats per scale k: GEMM  fmap_k (B*Ck x K=n^2)  @  prf_k^T (K x V)
// Fused epilogue: feats tile * w'[c,v], c-reduced, atomicAdd into out
// (pre-initialized with off[v] = bias - sum m*w').
//
// R14 = REVERT to the proven-best round-9 structure (110.2us):
//   * A staged RAW FP32 via global_load_lds into a single 32KB swizzled LDS
//     tile (inverse-swizzled per-lane source), cvt on the fragment read.
//   * B staged via global_load_lds from pre-swizzled bf16 images (16KB).
//   * 2 __syncthreads per step, 3 blocks/CU, one mega launch with
//     XCD-quad-preserving swizzle + single-step tail blocks.
// ONE banked delta (validated in R11-R14, epilogue-only): w' stored
// TRANSPOSED (wpt[v][c]) and read as f32x4 -> 16 coalesced dwordx4 per wave
// instead of 64 stride-2KB scalar loads.
// All pipelining variants (dbuf, counted-vmcnt, B-to-reg) measured slower:
// R10=119, R12=146, R13=138, R14=129 vs this structure's 110.
// ---------------------------------------------------------------------------

typedef float f32x4 __attribute__((ext_vector_type(4)));
typedef f32x4 __attribute__((aligned(4))) f32x4u;
typedef __bf16 bf16x4 __attribute__((ext_vector_type(4)));
typedef __bf16 bf16x8 __attribute__((ext_vector_type(8)));

#define TILE_E 8192              // elems per [128x64] tile
#define V_DIM 512
#define C_TOT 960
#define B_DIM 128

#define NBT 268                  // B tiles: 4 col-groups x (49+13+4+1)
#define NRA 896                  // ragged-A images: 128(s1)+256(s2)+512(s3)
#define PREP_WP 1920
#define PREP_OFF 512
#define PREP_BLKS (NBT + NRA + PREP_WP + PREP_OFF)

#define GEMM_BLKS 6144           // 1024(s0)+512(s1)+1024(s2)+3584(tail) = 8*768

// workspace layout (bytes): [wpt][bt][ra]
#define WP_BYTES 1966080L                   // 960*512*4 (v-major w')
#define BT_BYTES ((long)NBT * TILE_E * 2)   // 4,390,912
#define RA_BYTES ((long)NRA * TILE_E * 2)   // 14,680,064
#define WS_NEED  (WP_BYTES + BT_BYTES + RA_BYTES)

static __device__ __forceinline__ bf16x8 cvt8(f32x4 lo, f32x4 hi) {
  return bf16x8{(__bf16)lo[0], (__bf16)lo[1], (__bf16)lo[2], (__bf16)lo[3],
                (__bf16)hi[0], (__bf16)hi[1], (__bf16)hi[2], (__bf16)hi[3]};
}

// T2 XOR-swizzle, 16B granularity, inside a [128][64]-elem bf16 tile
static __device__ __forceinline__ int swz_idx(int row, int k) {
  return row * 64 + (((k >> 3) ^ (row & 7)) << 3) + (k & 7);
}

// ---------------------------------------------------------------------------
// Fused GEMM, single launch (requires ws). Decode after XCD interleave:
//   w in [0,1024): s0 full steps (fp32-A), split-K x4
//   w in [1024,1536): s1 full steps 0..11
//   w in [1536,2560): s2 full steps 0..2
//   w in [2560,6144): tail (1 bf16-image step): s1@12, s2@3, s3@0
// ---------------------------------------------------------------------------
__global__ __launch_bounds__(256, 3)
void gemm_all(const float* __restrict__ f0, const float* __restrict__ f1,
              const float* __restrict__ f2,
              const __bf16* __restrict__ bt,   // B tile images (pre-swizzled)
              const __bf16* __restrict__ ra,   // ragged-A tile images
              const float* __restrict__ wpt,   // [V, C_TOT] transposed w'
              float* __restrict__ out)         // [B, V]
{
  __shared__ float  lds_af[TILE_E];   // 32 KB fp32 A (tail reuses as bf16)
  __shared__ __bf16 lds_b[TILE_E];    // 16 KB B

  const int tid  = threadIdx.x;
  const int lane = tid & 63;
  const int wid  = tid >> 6;
  const int wm   = wid >> 1;
  const int wn   = wid & 1;

  // XCD-interleaved, x-quad-preserving decode: each XCD gets every-8th quad
  // of the LPT-ordered (longest-first) work list; 4 N-siblings co-locate.
  const int bid   = blockIdx.x;
  const int sslot = bid >> 3;
  const int xcd   = bid & 7;
  const int w     = (((sslot >> 2) << 3) + xcd) * 4 + (sslot & 3);

  f32x4 acc[4][4];
#pragma unroll
  for (int i = 0; i < 4; ++i)
#pragma unroll
    for (int j = 0; j < 4; ++j)
      acc[i][j] = f32x4{0.f, 0.f, 0.f, 0.f};

  int Ck, Coff, bn_g, bn;
  long bm;

  if (w < 2560) {
    // ======================= MAIN: fp32-A full steps =======================
    const float* fmap; int K, nst, bbase, y, s0k, sendk;
    if (w < 1024) {
      fmap = f0; K = 3136; nst = 49; bbase = 0; Ck = 64; Coff = 0;
      bn_g = w & 3; y = (w >> 2) & 63;
      const int z = w >> 8; s0k = z * 12; sendk = (z == 3) ? 49 : s0k + 12;
    } else if (w < 1536) {
      const int l = w - 1024;
      fmap = f1; K = 784; nst = 13; bbase = 196; Ck = 128; Coff = 64;
      bn_g = l & 3; y = l >> 2; s0k = 0; sendk = 12;
    } else {
      const int l = w - 1536;
      fmap = f2; K = 196; nst = 4; bbase = 248; Ck = 256; Coff = 192;
      bn_g = l & 3; y = l >> 2; s0k = 0; sendk = 3;
    }
    bm = (long)y * 128; bn = bn_g * 128;

    for (int ks = s0k; ks < sendk; ++ks) {
      __syncthreads();   // previous step's LDS readers done

      // stage A: raw fp32, inverse-swizzled per-lane source, linear LDS dest
      const float* ab = fmap + bm * (long)K + (long)ks * 64;
#pragma unroll
      for (int i = 0; i < 8; ++i) {
        const int seg = wid * 8 + i;
        const int cc  = seg * 64 + lane;       // dest 16B-chunk 0..2047
        const int row = cc >> 4;
        const int q4  = (cc & 15) ^ (row & 7); // source 4-float chunk
        __builtin_amdgcn_global_load_lds(
            (const __attribute__((address_space(1))) void*)(ab + (long)row * K + q4 * 4),
            (__attribute__((address_space(3))) void*)(&lds_af[seg * 256]),
            16, 0, 0);
      }
      // stage B: pre-swizzled bf16 image, linear copy
      const __bf16* bsrc = bt + (long)(bbase + bn_g * nst + ks) * TILE_E;
#pragma unroll
      for (int i = 0; i < 4; ++i) {
        const int seg = wid * 4 + i;
        __builtin_amdgcn_global_load_lds(
            (const __attribute__((address_space(1))) void*)(bsrc + seg * 512 + lane * 8),
            (__attribute__((address_space(3))) void*)(&lds_b[seg * 512]),
            16, 0, 0);
      }
      __syncthreads();   // drains gl_lds (vmcnt) + ds writes

      // fragments: A = 2x ds_read_b128 fp32 + cast; B = bf16 ds_read_b128
#pragma unroll
      for (int kc = 0; kc < 2; ++kc) {
        const int q4a = kc * 8 + ((lane >> 4) << 1);
        const int cx  = kc * 4 + (lane >> 4);
        bf16x8 af[4], bfr[4];
#pragma unroll
        for (int i = 0; i < 4; ++i) {
          const int r = wm * 64 + i * 16 + (lane & 15);
          const f32x4 fa = *(const f32x4*)&lds_af[r * 64 + ((q4a ^ (r & 7)) << 2)];
          const f32x4 fb = *(const f32x4*)&lds_af[r * 64 + (((q4a + 1) ^ (r & 7)) << 2)];
          af[i] = cvt8(fa, fb);
        }
#pragma unroll
        for (int j = 0; j < 4; ++j) {
          const int r = wn * 64 + j * 16 + (lane & 15);
          bfr[j] = *(const bf16x8*)&lds_b[r * 64 + ((cx ^ (r & 7)) << 3)];
        }
#pragma unroll
        for (int i = 0; i < 4; ++i)
#pragma unroll
          for (int j = 0; j < 4; ++j)
            acc[i][j] = __builtin_amdgcn_mfma_f32_16x16x32_bf16(af[i], bfr[j],
                                                                acc[i][j], 0, 0, 0);
      }
    }
  } else {
    // ================== TAIL: one bf16-image step per block =================
    const int l = w - 2560;
    int y, btile;
    long raidx;
    if (l < 512) {
      y = l >> 2; bn_g = l & 3; raidx = y;          Ck = 128; Coff = 64;
      btile = 196 + bn_g * 13 + 12;
    } else if (l < 1536) {
      const int m = l - 512;
      y = m >> 2; bn_g = m & 3; raidx = 128 + y;    Ck = 256; Coff = 192;
      btile = 248 + bn_g * 4 + 3;
    } else {
      const int m = l - 1536;
      y = m >> 2; bn_g = m & 3; raidx = 384 + y;    Ck = 512; Coff = 448;
      btile = 264 + bn_g;
    }
    bm = (long)y * 128; bn = bn_g * 128;

    __bf16* lds_ab = (__bf16*)lds_af;
    const __bf16* asrc = ra + raidx * TILE_E;
    const __bf16* bsrc = bt + (long)btile * TILE_E;
#pragma unroll
    for (int i = 0; i < 4; ++i) {
      const int seg = wid * 4 + i;
      __builtin_amdgcn_global_load_lds(
          (const __attribute__((address_space(1))) void*)(asrc + seg * 512 + lane * 8),
          (__attribute__((address_space(3))) void*)(&lds_ab[seg * 512]),
          16, 0, 0);
      __builtin_amdgcn_global_load_lds(
          (const __attribute__((address_space(1))) void*)(bsrc + seg * 512 + lane * 8),
          (__attribute__((address_space(3))) void*)(&lds_b[seg * 512]),
          16, 0, 0);
    }
    __syncthreads();

#pragma unroll
    for (int kc = 0; kc < 2; ++kc) {
      const int cx = kc * 4 + (lane >> 4);
      bf16x8 af[4], bfr[4];
#pragma unroll
      for (int i = 0; i < 4; ++i) {
        const int r = wm * 64 + i * 16 + (lane & 15);
        af[i] = *(const bf16x8*)&lds_ab[r * 64 + ((cx ^ (r & 7)) << 3)];
      }
#pragma unroll
      for (int j = 0; j < 4; ++j) {
        const int r = wn * 64 + j * 16 + (lane & 15);
        bfr[j] = *(const bf16x8*)&lds_b[r * 64 + ((cx ^ (r & 7)) << 3)];
      }
#pragma unroll
      for (int i = 0; i < 4; ++i)
#pragma unroll
        for (int j = 0; j < 4; ++j)
          acc[i][j] = __builtin_amdgcn_mfma_f32_16x16x32_bf16(af[i], bfr[j],
                                                              acc[i][j], 0, 0, 0);
    }
  }

  // ---- epilogue: per-wave 64x64 feats sub-tile, c-reduce, atomicAdd.
  // C/D layout: frag row = (lane>>4)*4 + reg, frag col = lane&15   [m89]
  // w' read vectorized from transposed wpt[v][c] (banked delta, R11-R14).
  const long mbase = bm + wm * 64;
  const int  bidx  = (int)(mbase / Ck);
  const int  cbase = (int)(mbase % Ck) + Coff;
  const int  lcol  = lane & 15;

#pragma unroll
  for (int j = 0; j < 4; ++j) {
    const int v = bn + wn * 64 + j * 16 + lcol;
    float s = 0.f;
#pragma unroll
    for (int i = 0; i < 4; ++i) {
      const int cg = cbase + i * 16 + ((lane >> 4) << 2);
      const f32x4 w4 = *(const f32x4*)&wpt[(long)v * C_TOT + cg];
      s += acc[i][j][0] * w4[0] + acc[i][j][1] * w4[1]
         + acc[i][j][2] * w4[2] + acc[i][j][3] * w4[3];
    }
    s += __shfl_xor(s, 16);
    s += __shfl_xor(s, 32);
    if (lane < 16)
      atomicAdd(&out[(long)bidx * V_DIM + v], s);
  }
}

// ---------------------------------------------------------------------------
// Convert one fp32 row-block into a bf16 pre-swizzled [128x64] tile image.
// img[swz_idx(row,k)] = src[rbase+row, ks*64+k], zero-padded past K.
// ---------------------------------------------------------------------------
static __device__ __forceinline__ void conv_tile(const float* __restrict__ src,
                                                 int K, long rbase, int ks,
                                                 __bf16* __restrict__ dst, int tid)
{
#pragma unroll
  for (int it = 0; it < 4; ++it) {
    const int u   = tid + it * 256;          // 1024 units of 8 elems
    const int row = u >> 3;
    const int q8  = u & 7;                   // stored 16B-chunk
    const int k   = ((q8 ^ (row & 7)) << 3); // source k
    const long gk = (long)ks * 64 + k;
    const float* sp = src + (rbase + row) * (long)K + gk;
    bf16x8 h;
    if (gk + 8 <= K) {
      h = cvt8(*(const f32x4u*)sp, *(const f32x4u*)(sp + 4));
    } else {
#pragma unroll
      for (int e = 0; e < 8; ++e)
        h[e] = (__bf16)((gk + e < K) ? sp[e] : 0.f);
    }
    *(bf16x8*)&dst[(long)row * 64 + q8 * 8] = h;
  }
}

// ---------------------------------------------------------------------------
// One prep launch: [0,268) B images; [268,1164) ragged-A images;
// then wpt (v-major w'); then out init with the constant term.
// ---------------------------------------------------------------------------
__global__ void prep_all(const float* __restrict__ f1, const float* __restrict__ f2,
                         const float* __restrict__ f3,
                         const float* __restrict__ p0, const float* __restrict__ p1,
                         const float* __restrict__ p2, const float* __restrict__ p3,
                         const float* __restrict__ weights,
                         const float* __restrict__ bias,
                         const float* __restrict__ fm,
                         const float* __restrict__ fs,
                         float* __restrict__ wpt,     // may be null
                         __bf16* __restrict__ bt,     // may be null
                         __bf16* __restrict__ ra,     // may be null
                         float* __restrict__ out)
{
  __shared__ float red[4];
  const int blk = blockIdx.x;
  const int tid = threadIdx.x;

  if (blk < NBT) {
    if (!bt) return;
    int t = blk; const float* src; int K, g, ks;
    if (t < 196)      { src = p0; K = 3136; g = t / 49; ks = t % 49; }
    else if (t < 248) { t -= 196; src = p1; K = 784; g = t / 13; ks = t % 13; }
    else if (t < 264) { t -= 248; src = p2; K = 196; g = t / 4;  ks = t % 4; }
    else              { t -= 264; src = p3; K = 49;  g = t;      ks = 0; }
    conv_tile(src, K, (long)g * 128, ks, bt + (long)blk * TILE_E, tid);
  } else if (blk < NBT + NRA) {
    if (!ra) return;
    const int t = blk - NBT; const float* src; int K, ks; long rbase;
    if (t < 128)      { src = f1; K = 784; ks = 12; rbase = (long)t * 128; }
    else if (t < 384) { src = f2; K = 196; ks = 3;  rbase = (long)(t - 128) * 128; }
    else              { src = f3; K = 49;  ks = 0;  rbase = (long)(t - 384) * 128; }
    conv_tile(src, K, rbase, ks, ra + (long)t * TILE_E, tid);
  } else if (blk < NBT + NRA + PREP_WP) {
    if (!wpt) return;
    const int idx = (blk - NBT - NRA) * 256 + tid;   // exactly 960*512
    const int v = idx / C_TOT;
    const int c = idx - v * C_TOT;
    wpt[idx] = weights[idx] / fs[(long)c * V_DIM + v];   // wpt layout == weights
  } else {
    const int v = blk - (NBT + NRA + PREP_WP);       // 0..511
    float s = 0.f;
    for (int c = tid; c < C_TOT; c += 256) {
      const long i = (long)c * V_DIM + v;
      s += fm[i] * weights[(long)v * C_TOT + c] / fs[i];
    }
#pragma unroll
    for (int o = 32; o; o >>= 1) s += __shfl_down(s, o);
    if ((tid & 63) == 0) red[tid >> 6] = s;
    __syncthreads();
    if (tid < B_DIM) {
      const float off = bias[v] - (red[0] + red[1] + red[2] + red[3]);
      out[(long)tid * V_DIM + v] = off;
    }
  }
}

// ---------------------------------------------------------------------------
// Fallback GEMM (ws too small): inline fp32 staging of both operands.
// ---------------------------------------------------------------------------
__global__ __launch_bounds__(256, 3)
void gemm_fb(const float* __restrict__ fmap, const float* __restrict__ prf,
             const float* __restrict__ weights, const float* __restrict__ fs,
             float* __restrict__ out,
             int Ck, int K, int Coff, int nsteps, int kchunks)
{
  __shared__ __bf16 lds_a[TILE_E];
  __shared__ __bf16 lds_b[TILE_E];
  const int tid = threadIdx.x, lane = tid & 63, wid = tid >> 6;
  const int wm = wid >> 1, wn = wid & 1;
  const long bm = (long)blockIdx.y * 128;
  const int bn = blockIdx.x * 128;
  const int z = blockIdx.z, qb = nsteps / kchunks, rb = nsteps % kchunks;
  const int s0 = z * qb + (z < rb ? z : rb);
  const int send = s0 + qb + (z < rb ? 1 : 0);

  f32x4 acc[4][4];
#pragma unroll
  for (int i = 0; i < 4; ++i)
#pragma unroll
    for (int j = 0; j < 4; ++j) acc[i][j] = f32x4{0.f, 0.f, 0.f, 0.f};

  for (int ks = s0; ks < send; ++ks) {
    __syncthreads();
#pragma unroll
    for (int i = 0; i < 8; ++i) {
      const int c = tid + i * 256, row = c >> 4, k0 = (c & 15) << 2;
      const long gk = (long)ks * 64 + k0;
      const float* ap = fmap + (bm + row) * (long)K + gk;
      const float* bp = prf + (long)(bn + row) * K + gk;
      float a[4], b[4];
#pragma unroll
      for (int e = 0; e < 4; ++e) {
        a[e] = (gk + e < K) ? ap[e] : 0.f;
        b[e] = (gk + e < K) ? bp[e] : 0.f;
      }
      bf16x4 ha = {(__bf16)a[0], (__bf16)a[1], (__bf16)a[2], (__bf16)a[3]};
      bf16x4 hb = {(__bf16)b[0], (__bf16)b[1], (__bf16)b[2], (__bf16)b[3]};
      *(bf16x4*)&lds_a[swz_idx(row, k0)] = ha;
      *(bf16x4*)&lds_b[swz_idx(row, k0)] = hb;
    }
    __syncthreads();
#pragma unroll
    for (int kc = 0; kc < 2; ++kc) {
      const int cx = kc * 4 + (lane >> 4);
      bf16x8 af[4], bfr[4];
#pragma unroll
      for (int i = 0; i < 4; ++i) {
        const int r = wm * 64 + i * 16 + (lane & 15);
        af[i] = *(const bf16x8*)&lds_a[r * 64 + ((cx ^ (r & 7)) << 3)];
      }
#pragma unroll
      for (int j = 0; j < 4; ++j) {
        const int r = wn * 64 + j * 16 + (lane & 15);
        bfr[j] = *(const bf16x8*)&lds_b[r * 64 + ((cx ^ (r & 7)) << 3)];
      }
#pragma unroll
      for (int i = 0; i < 4; ++i)
#pragma unroll
        for (int j = 0; j < 4; ++j)
          acc[i][j] = __builtin_amdgcn_mfma_f32_16x16x32_bf16(af[i], bfr[j],
                                                              acc[i][j], 0, 0, 0);
    }
  }

  const long mbase = bm + wm * 64;
  const int bidx = (int)(mbase / Ck);
  const int cbase = (int)(mbase % Ck) + Coff;
  const int lrow = ((lane >> 4) << 2), lcol = lane & 15;
#pragma unroll
  for (int j = 0; j < 4; ++j) {
    const int v = bn + wn * 64 + j * 16 + lcol;
    float s = 0.f;
#pragma unroll
    for (int i = 0; i < 4; ++i) {
      const int cg = cbase + i * 16 + lrow;
#pragma unroll
      for (int r = 0; r < 4; ++r) {
        const float wf = weights[(long)v * C_TOT + cg + r]
                         / fs[(long)(cg + r) * V_DIM + v];
        s += acc[i][j][r] * wf;
      }
    }
    s += __shfl_xor(s, 16);
    s += __shfl_xor(s, 32);
    if (lane < 16) atomicAdd(&out[(long)bidx * V_DIM + v], s);
  }
}

extern "C" void kernel_launch(void* const* d_in, const int* in_sizes, int n_in,
                              void* d_out, int out_size, void* d_ws, size_t ws_size,
                              hipStream_t stream)
{
  const float* fmap0   = (const float*)d_in[0];
  const float* prf0    = (const float*)d_in[1];
  const float* fmap1   = (const float*)d_in[2];
  const float* prf1    = (const float*)d_in[3];
  const float* fmap2   = (const float*)d_in[4];
  const float* prf2    = (const float*)d_in[5];
  const float* fmap3   = (const float*)d_in[6];
  const float* prf3    = (const float*)d_in[7];
  const float* weights = (const float*)d_in[8];
  const float* bias    = (const float*)d_in[9];
  const float* fm      = (const float*)d_in[10];
  const float* fs      = (const float*)d_in[11];
  float* out = (float*)d_out;

  const bool has_ws = ws_size >= (size_t)WS_NEED;
  float*  wpt = has_ws ? (float*)d_ws : nullptr;
  __bf16* bt  = has_ws ? (__bf16*)((char*)d_ws + WP_BYTES) : nullptr;
  __bf16* ra  = has_ws ? (__bf16*)((char*)d_ws + WP_BYTES + BT_BYTES) : nullptr;

  // 1) prep: B images + ragged-A images + wpt + out init
  prep_all<<<dim3(PREP_BLKS), dim3(256), 0, stream>>>(
      fmap1, fmap2, fmap3, prf0, prf1, prf2, prf3,
      weights, bias, fm, fs, wpt, bt, ra, out);

  // 2) single fused GEMM launch (main fp32-A path + image tail path)
  if (has_ws) {
    gemm_all<<<dim3(GEMM_BLKS), dim3(256), 0, stream>>>(
        fmap0, fmap1, fmap2, bt, ra, wpt, out);
  } else {
    struct Scale { const float* fmap; const float* prf; int Ck, K, Coff, nst, kch; };
    const Scale sc[4] = {
      {fmap0, prf0,  64, 3136,   0, 49, 4},
      {fmap1, prf1, 128,  784,  64, 13, 2},
      {fmap2, prf2, 256,  196, 192,  4, 1},
      {fmap3, prf3, 512,   49, 448,  1, 1},
    };
    for (int k = 0; k < 4; ++k) {
      dim3 grid(4, B_DIM * sc[k].Ck / 128, sc[k].kch);
      gemm_fb<<<grid, dim3(256), 0, stream>>>(
          sc[k].fmap, sc[k].prf, weights, fs, out,
          sc[k].Ck, sc[k].K, sc[k].Coff, sc[k].nst, sc[k].kch);
    }
  }
}

// Round 16
// 110.200 us; speedup vs baseline: 1.3211x; 1.1230x over previous
//
#include <hip/hip_runtime.h>

// ---------------------------------------------------------------------------
// r[b,v] = sum_c (feats[b,c,v] - m[c,v]) / s[c,v] * weights[v,c] + bias[v]
// feats per scale k: GEMM  fmap_k (B*Ck x K=n^2)  @  prf_k^T (K x V)
// Fused epilogue: feats tile * w'[c,v]=weights[v,c]/s[c,v], c-reduced,
// atomicAdd into out (pre-initialized with off[v] = bias - sum m*w').
//
// R15 = EXACT revert to the round-9 kernel (best measured: 110.2us).
//   * A staged RAW FP32 via global_load_lds into a 32KB swizzled LDS tile
//     (inverse-swizzled per-lane source), cvt to bf16 on the fragment read.
//   * B staged via global_load_lds from pre-swizzled bf16 images (16KB).
//   * 2 __syncthreads per step, 3 blocks/CU, one mega launch with
//     XCD-quad-preserving swizzle + single-step tail blocks.
//   * Epilogue reads w' from C-MAJOR wp[c][v]: lanes read consecutive v ->
//     fully coalesced. (R15's "vectorized" wpt[v][c] f32x4 was a per-lane
//     stride-3840B gather: -12us. Reverted.)
// Measured-worse variants: dbuf 1-barrier (119), B-to-reg spilled (146),
// counted-vmcnt @2blk/CU (138), B-to-reg clean (129), wpt epilogue (124),
// zero-LDS (206), 8-wave BN=512 (365). This structure is the local optimum.
// ---------------------------------------------------------------------------

typedef float f32x4 __attribute__((ext_vector_type(4)));
typedef f32x4 __attribute__((aligned(4))) f32x4u;
typedef __bf16 bf16x4 __attribute__((ext_vector_type(4)));
typedef __bf16 bf16x8 __attribute__((ext_vector_type(8)));

#define TILE_E 8192              // 128x64 elems per tile
#define V_DIM 512
#define C_TOT 960
#define B_DIM 128

#define NBT 268                  // B tiles (all steps, all scales)
#define NRA 896                  // ragged A tiles: 128(s1) + 256(s2) + 512(s3)
#define PREP_WP 1920
#define PREP_OFF 512
#define PREP_BLKS (NBT + NRA + PREP_WP + PREP_OFF)

#define GEMM_BLKS 6144           // 1024(s0) + 512(s1) + 1024(s2) + 3584(tail) = 8*768

// workspace layout (bytes): [wp][bt][ra]
#define WP_BYTES 1966080L
#define BT_BYTES ((long)NBT * TILE_E * 2)   // 4,390,912
#define RA_BYTES ((long)NRA * TILE_E * 2)   // 14,680,064
#define WS_NEED  (WP_BYTES + BT_BYTES + RA_BYTES)

// T2 XOR-swizzle, 16B granularity, inside a [128][64]-elem tile
static __device__ __forceinline__ int swz_idx(int row, int k) {   // bf16 elems
  return row * 64 + (((k >> 3) ^ (row & 7)) << 3) + (k & 7);
}

static __device__ __forceinline__ bf16x8 cvt8(f32x4 lo, f32x4 hi) {
  return bf16x8{(__bf16)lo[0], (__bf16)lo[1], (__bf16)lo[2], (__bf16)lo[3],
                (__bf16)hi[0], (__bf16)hi[1], (__bf16)hi[2], (__bf16)hi[3]};
}

// ---------------------------------------------------------------------------
// Fused GEMM, single launch. Block decode (after XCD interleave):
//   w in [0,1024): s0 full steps (fp32-A), 64y*4x*4z, steps 12/12/12/13
//   w in [1024,1536): s1 full steps 0..11
//   w in [1536,2560): s2 full steps 0..2
//   w in [2560,6144): tail (1 bf16-image step): s1@12, s2@3, s3@0
// ---------------------------------------------------------------------------
__global__ __launch_bounds__(256, 3)
void gemm_all(const float* __restrict__ f0, const float* __restrict__ f1,
              const float* __restrict__ f2,
              const __bf16* __restrict__ bt,   // B tile images
              const __bf16* __restrict__ ra,   // ragged-A tile images
              const float* __restrict__ wp,    // [C_TOT, V]
              float* __restrict__ out)         // [B, V]
{
  __shared__ float  lds_af[TILE_E];   // 32 KB fp32 A (tail reuses as bf16)
  __shared__ __bf16 lds_b[TILE_E];    // 16 KB B

  const int tid  = threadIdx.x;
  const int lane = tid & 63;
  const int wid  = tid >> 6;
  const int wm   = wid >> 1;
  const int wn   = wid & 1;

  // XCD-interleaved, x-quad-preserving decode: each XCD gets every-8th quad
  // of the LPT-ordered (longest-first) work list; 4 N-siblings co-locate.
  const int bid   = blockIdx.x;
  const int sslot = bid >> 3;
  const int xcd   = bid & 7;
  const int w     = (((sslot >> 2) << 3) + xcd) * 4 + (sslot & 3);

  f32x4 acc[4][4];
#pragma unroll
  for (int i = 0; i < 4; ++i)
#pragma unroll
    for (int j = 0; j < 4; ++j)
      acc[i][j] = f32x4{0.f, 0.f, 0.f, 0.f};

  int Ck, Coff, bn_g, bn;
  long bm;

  if (w < 2560) {
    // ======================= MAIN: fp32-A full steps =======================
    const float* fmap; int K, nst, bbase, y, s0k, sendk;
    if (w < 1024) {
      fmap = f0; K = 3136; nst = 49; bbase = 0; Ck = 64; Coff = 0;
      bn_g = w & 3; y = (w >> 2) & 63;
      const int z = w >> 8; s0k = z * 12; sendk = (z == 3) ? 49 : s0k + 12;
    } else if (w < 1536) {
      const int l = w - 1024;
      fmap = f1; K = 784; nst = 13; bbase = 196; Ck = 128; Coff = 64;
      bn_g = l & 3; y = l >> 2; s0k = 0; sendk = 12;
    } else {
      const int l = w - 1536;
      fmap = f2; K = 196; nst = 4; bbase = 248; Ck = 256; Coff = 192;
      bn_g = l & 3; y = l >> 2; s0k = 0; sendk = 3;
    }
    bm = (long)y * 128; bn = bn_g * 128;

    for (int ks = s0k; ks < sendk; ++ks) {
      __syncthreads();   // previous step's LDS readers done

      // stage A: raw fp32, inverse-swizzled per-lane source, linear LDS dest
      const float* ab = fmap + bm * (long)K + (long)ks * 64;
#pragma unroll
      for (int i = 0; i < 8; ++i) {
        const int seg = wid * 8 + i;
        const int cc  = seg * 64 + lane;       // dest 16B-chunk 0..2047
        const int row = cc >> 4;
        const int q4  = (cc & 15) ^ (row & 7); // source 4-float chunk
        __builtin_amdgcn_global_load_lds(
            (const __attribute__((address_space(1))) void*)(ab + (long)row * K + q4 * 4),
            (__attribute__((address_space(3))) void*)(&lds_af[seg * 256]),
            16, 0, 0);
      }
      // stage B: pre-swizzled bf16 image, linear copy
      const __bf16* bsrc = bt + (long)(bbase + bn_g * nst + ks) * TILE_E;
#pragma unroll
      for (int i = 0; i < 4; ++i) {
        const int seg = wid * 4 + i;
        __builtin_amdgcn_global_load_lds(
            (const __attribute__((address_space(1))) void*)(bsrc + seg * 512 + lane * 8),
            (__attribute__((address_space(3))) void*)(&lds_b[seg * 512]),
            16, 0, 0);
      }
      __syncthreads();   // drains gl_lds (vmcnt) + ds writes

      // fragments: A = 2x ds_read_b128 fp32 + cast; B = bf16 ds_read_b128
#pragma unroll
      for (int kc = 0; kc < 2; ++kc) {
        const int q4a = kc * 8 + ((lane >> 4) << 1);
        const int cx  = kc * 4 + (lane >> 4);
        bf16x8 af[4], bfr[4];
#pragma unroll
        for (int i = 0; i < 4; ++i) {
          const int r = wm * 64 + i * 16 + (lane & 15);
          const f32x4 fa = *(const f32x4*)&lds_af[r * 64 + ((q4a ^ (r & 7)) << 2)];
          const f32x4 fb = *(const f32x4*)&lds_af[r * 64 + (((q4a + 1) ^ (r & 7)) << 2)];
          af[i] = cvt8(fa, fb);
        }
#pragma unroll
        for (int j = 0; j < 4; ++j) {
          const int r = wn * 64 + j * 16 + (lane & 15);
          bfr[j] = *(const bf16x8*)&lds_b[r * 64 + ((cx ^ (r & 7)) << 3)];
        }
#pragma unroll
        for (int i = 0; i < 4; ++i)
#pragma unroll
          for (int j = 0; j < 4; ++j)
            acc[i][j] = __builtin_amdgcn_mfma_f32_16x16x32_bf16(af[i], bfr[j],
                                                                acc[i][j], 0, 0, 0);
      }
    }
  } else {
    // ================== TAIL: one bf16-image step per block =================
    const int l = w - 2560;
    int y, btile;
    long raidx;
    if (l < 512) {
      y = l >> 2; bn_g = l & 3; raidx = y;          Ck = 128; Coff = 64;
      btile = 196 + bn_g * 13 + 12;
    } else if (l < 1536) {
      const int m = l - 512;
      y = m >> 2; bn_g = m & 3; raidx = 128 + y;    Ck = 256; Coff = 192;
      btile = 248 + bn_g * 4 + 3;
    } else {
      const int m = l - 1536;
      y = m >> 2; bn_g = m & 3; raidx = 384 + y;    Ck = 512; Coff = 448;
      btile = 264 + bn_g;
    }
    bm = (long)y * 128; bn = bn_g * 128;

    __bf16* lds_ab = (__bf16*)lds_af;
    const __bf16* asrc = ra + raidx * TILE_E;
    const __bf16* bsrc = bt + (long)btile * TILE_E;
#pragma unroll
    for (int i = 0; i < 4; ++i) {
      const int seg = wid * 4 + i;
      __builtin_amdgcn_global_load_lds(
          (const __attribute__((address_space(1))) void*)(asrc + seg * 512 + lane * 8),
          (__attribute__((address_space(3))) void*)(&lds_ab[seg * 512]),
          16, 0, 0);
      __builtin_amdgcn_global_load_lds(
          (const __attribute__((address_space(1))) void*)(bsrc + seg * 512 + lane * 8),
          (__attribute__((address_space(3))) void*)(&lds_b[seg * 512]),
          16, 0, 0);
    }
    __syncthreads();

#pragma unroll
    for (int kc = 0; kc < 2; ++kc) {
      const int cx = kc * 4 + (lane >> 4);
      bf16x8 af[4], bfr[4];
#pragma unroll
      for (int i = 0; i < 4; ++i) {
        const int r = wm * 64 + i * 16 + (lane & 15);
        af[i] = *(const bf16x8*)&lds_ab[r * 64 + ((cx ^ (r & 7)) << 3)];
      }
#pragma unroll
      for (int j = 0; j < 4; ++j) {
        const int r = wn * 64 + j * 16 + (lane & 15);
        bfr[j] = *(const bf16x8*)&lds_b[r * 64 + ((cx ^ (r & 7)) << 3)];
      }
#pragma unroll
      for (int i = 0; i < 4; ++i)
#pragma unroll
        for (int j = 0; j < 4; ++j)
          acc[i][j] = __builtin_amdgcn_mfma_f32_16x16x32_bf16(af[i], bfr[j],
                                                              acc[i][j], 0, 0, 0);
    }
  }

  // ---- epilogue: per-wave 64x64 feats sub-tile, c-reduce, atomicAdd.
  // C/D layout: frag row = (lane>>4)*4 + reg, frag col = lane&15   [m89]
  // wp is C-MAJOR: for fixed c, lanes read consecutive v -> coalesced.
  const long mbase = bm + wm * 64;
  const int  bidx  = (int)(mbase / Ck);
  const int  cbase = (int)(mbase % Ck) + Coff;
  const int  lrow  = ((lane >> 4) << 2);
  const int  lcol  = lane & 15;

#pragma unroll
  for (int j = 0; j < 4; ++j) {
    const int v = bn + wn * 64 + j * 16 + lcol;
    float s = 0.f;
#pragma unroll
    for (int i = 0; i < 4; ++i) {
      const int cg = cbase + i * 16 + lrow;
#pragma unroll
      for (int r = 0; r < 4; ++r)
        s += acc[i][j][r] * wp[(long)(cg + r) * V_DIM + v];
    }
    s += __shfl_xor(s, 16);
    s += __shfl_xor(s, 32);
    if (lane < 16)
      atomicAdd(&out[(long)bidx * V_DIM + v], s);
  }
}

// ---------------------------------------------------------------------------
// Convert one fp32 source panel row-block into a bf16 pre-swizzled tile image.
// Image: img[swz_idx(row,k)] = src[rbase+row, ks*64+k], zero-padded past K.
// ---------------------------------------------------------------------------
static __device__ __forceinline__ void conv_tile(const float* __restrict__ src,
                                                 int K, long rbase, int ks,
                                                 __bf16* __restrict__ dst, int tid)
{
#pragma unroll
  for (int it = 0; it < 4; ++it) {
    const int u   = tid + it * 256;          // 1024 units of 8 elems
    const int row = u >> 3;
    const int q8  = u & 7;                   // swizzled 16B-chunk index
    const int k   = ((q8 ^ (row & 7)) << 3); // source k of this chunk
    const long gk = (long)ks * 64 + k;
    const float* sp = src + (rbase + row) * (long)K + gk;
    bf16x8 h;
    if (gk + 8 <= K) {
      const f32x4u a = *(const f32x4u*)sp;
      const f32x4u b = *(const f32x4u*)(sp + 4);
      h = cvt8(f32x4{a[0], a[1], a[2], a[3]}, f32x4{b[0], b[1], b[2], b[3]});
    } else {
#pragma unroll
      for (int e = 0; e < 8; ++e)
        h[e] = (__bf16)((gk + e < K) ? sp[e] : 0.f);
    }
    *(bf16x8*)&dst[(long)row * 64 + q8 * 8] = h;
  }
}

// ---------------------------------------------------------------------------
// One prep launch: [0,268) B images; [268,1164) ragged-A images;
// then wp (c-major w'); then out init with the constant term.
// ---------------------------------------------------------------------------
__global__ void prep_all(const float* __restrict__ f1, const float* __restrict__ f2,
                         const float* __restrict__ f3,
                         const float* __restrict__ p0, const float* __restrict__ p1,
                         const float* __restrict__ p2, const float* __restrict__ p3,
                         const float* __restrict__ weights,
                         const float* __restrict__ bias,
                         const float* __restrict__ fm,
                         const float* __restrict__ fs,
                         float* __restrict__ wp,      // may be null
                         __bf16* __restrict__ bt,     // may be null
                         __bf16* __restrict__ ra,     // may be null
                         float* __restrict__ out)
{
  __shared__ float red[4];
  const int blk = blockIdx.x;
  const int tid = threadIdx.x;

  if (blk < NBT) {
    if (!bt) return;
    int t = blk; const float* src; int K, g, ks;
    if (t < 196)      { src = p0; K = 3136; g = t / 49; ks = t % 49; }
    else if (t < 248) { t -= 196; src = p1; K = 784; g = t / 13; ks = t % 13; }
    else if (t < 264) { t -= 248; src = p2; K = 196; g = t / 4;  ks = t % 4; }
    else              { t -= 264; src = p3; K = 49;  g = t;      ks = 0; }
    conv_tile(src, K, (long)g * 128, ks, bt + (long)blk * TILE_E, tid);
  } else if (blk < NBT + NRA) {
    if (!ra) return;
    const int t = blk - NBT; const float* src; int K, ks; long rbase;
    if (t < 128)      { src = f1; K = 784; ks = 12; rbase = (long)t * 128; }
    else if (t < 384) { src = f2; K = 196; ks = 3;  rbase = (long)(t - 128) * 128; }
    else              { src = f3; K = 49;  ks = 0;  rbase = (long)(t - 384) * 128; }
    conv_tile(src, K, rbase, ks, ra + (long)t * TILE_E, tid);
  } else if (blk < NBT + NRA + PREP_WP) {
    if (!wp) return;
    const int idx = (blk - NBT - NRA) * 256 + tid;   // exactly 960*512
    const int c = idx >> 9;
    const int v = idx & (V_DIM - 1);
    wp[idx] = weights[(long)v * C_TOT + c] / fs[idx];
  } else {
    const int v = blk - (NBT + NRA + PREP_WP);       // 0..511
    float s = 0.f;
    for (int c = tid; c < C_TOT; c += 256) {
      const long i = (long)c * V_DIM + v;
      s += fm[i] * weights[(long)v * C_TOT + c] / fs[i];
    }
#pragma unroll
    for (int o = 32; o; o >>= 1) s += __shfl_down(s, o);
    if ((tid & 63) == 0) red[tid >> 6] = s;
    __syncthreads();
    if (tid < B_DIM) {
      const float off = bias[v] - (red[0] + red[1] + red[2] + red[3]);
      out[(long)tid * V_DIM + v] = off;
    }
  }
}

// ---------------------------------------------------------------------------
// Fallback GEMM (ws too small): inline fp32 staging of both operands.
// ---------------------------------------------------------------------------
__global__ __launch_bounds__(256, 3)
void gemm_fb(const float* __restrict__ fmap, const float* __restrict__ prf,
             const float* __restrict__ weights, const float* __restrict__ fs,
             float* __restrict__ out,
             int Ck, int K, int Coff, int nsteps, int kchunks)
{
  __shared__ __bf16 lds_a[TILE_E];
  __shared__ __bf16 lds_b[TILE_E];
  const int tid = threadIdx.x, lane = tid & 63, wid = tid >> 6;
  const int wm = wid >> 1, wn = wid & 1;
  const long bm = (long)blockIdx.y * 128;
  const int bn = blockIdx.x * 128;
  const int z = blockIdx.z, qb = nsteps / kchunks, rb = nsteps % kchunks;
  const int s0 = z * qb + (z < rb ? z : rb);
  const int send = s0 + qb + (z < rb ? 1 : 0);

  f32x4 acc[4][4];
#pragma unroll
  for (int i = 0; i < 4; ++i)
#pragma unroll
    for (int j = 0; j < 4; ++j) acc[i][j] = f32x4{0.f, 0.f, 0.f, 0.f};

  for (int ks = s0; ks < send; ++ks) {
    __syncthreads();
#pragma unroll
    for (int i = 0; i < 8; ++i) {
      const int c = tid + i * 256, row = c >> 4, k0 = (c & 15) << 2;
      const long gk = (long)ks * 64 + k0;
      const float* ap = fmap + (bm + row) * (long)K + gk;
      const float* bp = prf + (long)(bn + row) * K + gk;
      float a[4], b[4];
#pragma unroll
      for (int e = 0; e < 4; ++e) {
        a[e] = (gk + e < K) ? ap[e] : 0.f;
        b[e] = (gk + e < K) ? bp[e] : 0.f;
      }
      bf16x4 ha = {(__bf16)a[0], (__bf16)a[1], (__bf16)a[2], (__bf16)a[3]};
      bf16x4 hb = {(__bf16)b[0], (__bf16)b[1], (__bf16)b[2], (__bf16)b[3]};
      *(bf16x4*)&lds_a[swz_idx(row, k0)] = ha;
      *(bf16x4*)&lds_b[swz_idx(row, k0)] = hb;
    }
    __syncthreads();
#pragma unroll
    for (int kc = 0; kc < 2; ++kc) {
      const int cx = kc * 4 + (lane >> 4);
      bf16x8 af[4], bfr[4];
#pragma unroll
      for (int i = 0; i < 4; ++i) {
        const int r = wm * 64 + i * 16 + (lane & 15);
        af[i] = *(const bf16x8*)&lds_a[r * 64 + ((cx ^ (r & 7)) << 3)];
      }
#pragma unroll
      for (int j = 0; j < 4; ++j) {
        const int r = wn * 64 + j * 16 + (lane & 15);
        bfr[j] = *(const bf16x8*)&lds_b[r * 64 + ((cx ^ (r & 7)) << 3)];
      }
#pragma unroll
      for (int i = 0; i < 4; ++i)
#pragma unroll
        for (int j = 0; j < 4; ++j)
          acc[i][j] = __builtin_amdgcn_mfma_f32_16x16x32_bf16(af[i], bfr[j],
                                                              acc[i][j], 0, 0, 0);
    }
  }

  const long mbase = bm + wm * 64;
  const int bidx = (int)(mbase / Ck);
  const int cbase = (int)(mbase % Ck) + Coff;
  const int lrow = ((lane >> 4) << 2), lcol = lane & 15;
#pragma unroll
  for (int j = 0; j < 4; ++j) {
    const int v = bn + wn * 64 + j * 16 + lcol;
    float s = 0.f;
#pragma unroll
    for (int i = 0; i < 4; ++i) {
      const int cg = cbase + i * 16 + lrow;
#pragma unroll
      for (int r = 0; r < 4; ++r) {
        const float wf = weights[(long)v * C_TOT + cg + r]
                         / fs[(long)(cg + r) * V_DIM + v];
        s += acc[i][j][r] * wf;
      }
    }
    s += __shfl_xor(s, 16);
    s += __shfl_xor(s, 32);
    if (lane < 16) atomicAdd(&out[(long)bidx * V_DIM + v], s);
  }
}

extern "C" void kernel_launch(void* const* d_in, const int* in_sizes, int n_in,
                              void* d_out, int out_size, void* d_ws, size_t ws_size,
                              hipStream_t stream)
{
  const float* fmap0   = (const float*)d_in[0];
  const float* prf0    = (const float*)d_in[1];
  const float* fmap1   = (const float*)d_in[2];
  const float* prf1    = (const float*)d_in[3];
  const float* fmap2   = (const float*)d_in[4];
  const float* prf2    = (const float*)d_in[5];
  const float* fmap3   = (const float*)d_in[6];
  const float* prf3    = (const float*)d_in[7];
  const float* weights = (const float*)d_in[8];
  const float* bias    = (const float*)d_in[9];
  const float* fm      = (const float*)d_in[10];
  const float* fs      = (const float*)d_in[11];
  float* out = (float*)d_out;

  const bool has_ws = ws_size >= (size_t)WS_NEED;
  float*  wp = has_ws ? (float*)d_ws : nullptr;
  __bf16* bt = has_ws ? (__bf16*)((char*)d_ws + WP_BYTES) : nullptr;
  __bf16* ra = has_ws ? (__bf16*)((char*)d_ws + WP_BYTES + BT_BYTES) : nullptr;

  // 1) prep: B images + ragged-A images + wp + out init
  prep_all<<<dim3(PREP_BLKS), dim3(256), 0, stream>>>(
      fmap1, fmap2, fmap3, prf0, prf1, prf2, prf3,
      weights, bias, fm, fs, wp, bt, ra, out);

  // 2) single fused GEMM launch (main fp32-A path + image tail path)
  if (has_ws) {
    gemm_all<<<dim3(GEMM_BLKS), dim3(256), 0, stream>>>(
        fmap0, fmap1, fmap2, bt, ra, wp, out);
  } else {
    struct Scale { const float* fmap; const float* prf; int Ck, K, Coff, nst, kch; };
    const Scale sc[4] = {
      {fmap0, prf0,  64, 3136,   0, 49, 4},
      {fmap1, prf1, 128,  784,  64, 13, 2},
      {fmap2, prf2, 256,  196, 192,  4, 1},
      {fmap3, prf3, 512,   49, 448,  1, 1},
    };
    for (int k = 0; k < 4; ++k) {
      dim3 grid(4, B_DIM * sc[k].Ck / 128, sc[k].kch);
      gemm_fb<<<grid, dim3(256), 0, stream>>>(
          sc[k].fmap, sc[k].prf, weights, fs, out,
          sc[k].Ck, sc[k].K, sc[k].Coff, sc[k].nst, sc[k].kch);
    }
  }
}